// Round 1
// baseline (9637.806 us; speedup 1.0000x reference)
//
#include <hip/hip_runtime.h>
#include <math.h>

// ---------------- helpers ----------------

__global__ void zero_f32(float* __restrict__ p, int n) {
    int i = blockIdx.x * blockDim.x + threadIdx.x;
    if (i < n) p[i] = 0.f;
}

__global__ void count_deg(const int* __restrict__ dst, float* __restrict__ deg, int E) {
    int i = blockIdx.x * blockDim.x + threadIdx.x;
    int stride = gridDim.x * blockDim.x;
    for (; i < E; i += stride) atomicAdd(&deg[dst[i]], 1.0f);
}

__global__ void finalize_dinv(float* __restrict__ d, int n) {
    int i = blockIdx.x * blockDim.x + threadIdx.x;
    if (i < n) d[i] = rsqrtf(d[i] + 1.0f);   // +1 for self-loop
}

__global__ void edge_norm_k(const int* __restrict__ src, const int* __restrict__ dst,
                            const float* __restrict__ dinv, float* __restrict__ en, int E) {
    int i = blockIdx.x * blockDim.x + threadIdx.x;
    int stride = gridDim.x * blockDim.x;
    for (; i < E; i += stride) en[i] = dinv[src[i]] * dinv[dst[i]];
}

// ---------------- GEMM: out[N,128] = (relu_in? relu(in) : in)[N,128] @ W[128,128] (+bias) ----------------
// W staged in LDS (64KB). One wave per row; lane computes outputs {lane, lane+64}.

__global__ __launch_bounds__(256) void gemm128(
    const float* __restrict__ in, const float* __restrict__ W,
    const float* __restrict__ bias, float* __restrict__ out,
    int n_rows, int relu_in, int relu_out)
{
    __shared__ float Wl[128 * 128];
    for (int i = threadIdx.x; i < 128 * 128; i += 256) Wl[i] = W[i];
    __syncthreads();

    int lane = threadIdx.x & 63;
    int wid  = (blockIdx.x * 256 + threadIdx.x) >> 6;
    int nw   = (gridDim.x * 256) >> 6;

    float bb0 = 0.f, bb1 = 0.f;
    if (bias) { bb0 = bias[lane]; bb1 = bias[lane + 64]; }

    for (int row = wid; row < n_rows; row += nw) {
        const float* xr = in + (size_t)row * 128;
        float a0 = bb0, a1 = bb1;
        #pragma unroll
        for (int k = 0; k < 128; k += 4) {
            float4 xv = *(const float4*)(xr + k);
            if (relu_in) {
                xv.x = fmaxf(xv.x, 0.f); xv.y = fmaxf(xv.y, 0.f);
                xv.z = fmaxf(xv.z, 0.f); xv.w = fmaxf(xv.w, 0.f);
            }
            a0 = fmaf(xv.x, Wl[(k + 0) * 128 + lane], a0);
            a1 = fmaf(xv.x, Wl[(k + 0) * 128 + 64 + lane], a1);
            a0 = fmaf(xv.y, Wl[(k + 1) * 128 + lane], a0);
            a1 = fmaf(xv.y, Wl[(k + 1) * 128 + 64 + lane], a1);
            a0 = fmaf(xv.z, Wl[(k + 2) * 128 + lane], a0);
            a1 = fmaf(xv.z, Wl[(k + 2) * 128 + 64 + lane], a1);
            a0 = fmaf(xv.w, Wl[(k + 3) * 128 + lane], a0);
            a1 = fmaf(xv.w, Wl[(k + 3) * 128 + 64 + lane], a1);
        }
        if (relu_out) { a0 = fmaxf(a0, 0.f); a1 = fmaxf(a1, 0.f); }
        out[(size_t)row * 128 + lane]      = a0;
        out[(size_t)row * 128 + 64 + lane] = a1;
    }
}

// ---------------- agg[n][f] = hW[n][f] * dinv[n]^2 + bias[f] ----------------

__global__ __launch_bounds__(256) void agg_init(
    const float* __restrict__ hW, const float* __restrict__ dinv,
    const float* __restrict__ bias, float* __restrict__ agg, int n)
{
    int i = blockIdx.x * blockDim.x + threadIdx.x;   // item = node*32 + chunk
    int stride = gridDim.x * blockDim.x;
    int total = n * 32;
    for (; i < total; i += stride) {
        int node = i >> 5, c = (i & 31) * 4;
        float sn = dinv[node]; sn *= sn;
        float4 h  = *(const float4*)(hW + (size_t)node * 128 + c);
        float4 bv = *(const float4*)(bias + c);
        float4 o;
        o.x = fmaf(h.x, sn, bv.x);
        o.y = fmaf(h.y, sn, bv.y);
        o.z = fmaf(h.z, sn, bv.z);
        o.w = fmaf(h.w, sn, bv.w);
        *(float4*)(agg + (size_t)node * 128 + c) = o;
    }
}

// ---------------- agg[dst] += hW[src] * en  (atomic scatter) ----------------
// 32 consecutive threads handle one edge's 128 floats (float4 each) -> coalesced gather.

__global__ __launch_bounds__(256) void scatter_add(
    const float* __restrict__ hW, const int* __restrict__ src, const int* __restrict__ dst,
    const float* __restrict__ en, float* __restrict__ agg, int E)
{
    long long i = (long long)blockIdx.x * blockDim.x + threadIdx.x;
    long long stride = (long long)gridDim.x * blockDim.x;
    long long total = (long long)E * 32;
    for (; i < total; i += stride) {
        int e = (int)(i >> 5);
        int c = (int)(i & 31) * 4;
        int s = src[e], d = dst[e];
        float w = en[e];
        float4 h = *(const float4*)(hW + (size_t)s * 128 + c);
        float* ap = agg + (size_t)d * 128 + c;
        atomicAdd(ap + 0, h.x * w);
        atomicAdd(ap + 1, h.y * w);
        atomicAdd(ap + 2, h.z * w);
        atomicAdd(ap + 3, h.w * w);
    }
}

// ---------------- out = log_softmax( h[N,128] @ W[128,40] + b ) ----------------
// One wave per row; lanes 0..39 hold the 40 logits; shuffle reductions.

__global__ __launch_bounds__(256) void lin2_lsm(
    const float* __restrict__ h, const float* __restrict__ W,
    const float* __restrict__ bias, float* __restrict__ out, int n)
{
    __shared__ float Wl[128 * 40];
    for (int i = threadIdx.x; i < 128 * 40; i += 256) Wl[i] = W[i];
    __syncthreads();

    int lane = threadIdx.x & 63;
    int wid  = (blockIdx.x * 256 + threadIdx.x) >> 6;
    int nw   = (gridDim.x * 256) >> 6;

    for (int row = wid; row < n; row += nw) {
        const float* xr = h + (size_t)row * 128;
        float acc = -INFINITY;
        if (lane < 40) {
            acc = bias[lane];
            for (int k = 0; k < 128; k++)
                acc = fmaf(xr[k], Wl[k * 40 + lane], acc);
        }
        float m = acc;
        #pragma unroll
        for (int off = 32; off >= 1; off >>= 1)
            m = fmaxf(m, __shfl_xor(m, off, 64));
        float ex = (lane < 40) ? __expf(acc - m) : 0.f;
        float s = ex;
        #pragma unroll
        for (int off = 32; off >= 1; off >>= 1)
            s += __shfl_xor(s, off, 64);
        float ls = __logf(s);
        if (lane < 40) out[(size_t)row * 40 + lane] = acc - m - ls;
    }
}

// ---------------- launch ----------------

extern "C" void kernel_launch(void* const* d_in, const int* in_sizes, int n_in,
                              void* d_out, int out_size, void* d_ws, size_t ws_size,
                              hipStream_t stream)
{
    const float* x   = (const float*)d_in[0];
    const int*   ei  = (const int*)d_in[1];
    const float* W1  = (const float*)d_in[2];  const float* b1  = (const float*)d_in[3];
    const float* W2  = (const float*)d_in[4];  const float* b2  = (const float*)d_in[5];
    const float* W3  = (const float*)d_in[6];  const float* b3  = (const float*)d_in[7];
    const float* l1w = (const float*)d_in[8];  const float* l1b = (const float*)d_in[9];
    const float* l2w = (const float*)d_in[10]; const float* l2b = (const float*)d_in[11];

    const int N = in_sizes[0] / 128;
    const int E = in_sizes[1] / 2;
    const int* src = ei;
    const int* dst = ei + E;

    float* ws   = (float*)d_ws;
    float* dinv = ws;                              // [N]
    float* en   = dinv + N;                        // [E]
    float* bufH = en + E;                          // [N*128]
    float* bufA = bufH + (size_t)N * 128;          // [N*128]

    float* outp = (float*)d_out;

    // norm precompute
    zero_f32<<<(N + 255) / 256, 256, 0, stream>>>(dinv, N);
    count_deg<<<2048, 256, 0, stream>>>(dst, dinv, E);
    finalize_dinv<<<(N + 255) / 256, 256, 0, stream>>>(dinv, N);
    edge_norm_k<<<2048, 256, 0, stream>>>(src, dst, dinv, en, E);

    // layer 1: in = x (no relu)
    gemm128<<<2048, 256, 0, stream>>>(x, W1, nullptr, bufH, N, 0, 0);
    agg_init<<<4096, 256, 0, stream>>>(bufH, dinv, b1, bufA, N);
    scatter_add<<<8192, 256, 0, stream>>>(bufH, src, dst, en, bufA, E);

    // layer 2: in = relu(bufA)
    gemm128<<<2048, 256, 0, stream>>>(bufA, W2, nullptr, bufH, N, 1, 0);
    agg_init<<<4096, 256, 0, stream>>>(bufH, dinv, b2, bufA, N);
    scatter_add<<<8192, 256, 0, stream>>>(bufH, src, dst, en, bufA, E);

    // layer 3: in = relu(bufA)
    gemm128<<<2048, 256, 0, stream>>>(bufA, W3, nullptr, bufH, N, 1, 0);
    agg_init<<<4096, 256, 0, stream>>>(bufH, dinv, b3, bufA, N);
    scatter_add<<<8192, 256, 0, stream>>>(bufH, src, dst, en, bufA, E);

    // lin1: relu in and out
    gemm128<<<2048, 256, 0, stream>>>(bufA, l1w, l1b, bufH, N, 1, 1);

    // lin2 + log_softmax
    lin2_lsm<<<2048, 256, 0, stream>>>(bufH, l2w, l2b, outp, N);
}

// Round 2
// 2553.049 us; speedup vs baseline: 3.7750x; 3.7750x over previous
//
#include <hip/hip_runtime.h>
#include <math.h>

// ---------------- degree / norm precompute ----------------

__global__ void zero_i32(int* __restrict__ p, int n) {
    int i = blockIdx.x * blockDim.x + threadIdx.x;
    if (i < n) p[i] = 0;
}

__global__ void count_deg(const int* __restrict__ dst, int* __restrict__ deg, int E) {
    int i = blockIdx.x * blockDim.x + threadIdx.x;
    int stride = gridDim.x * blockDim.x;
    for (; i < E; i += stride) atomicAdd(&deg[dst[i]], 1);
}

__global__ void finalize_dinv(const int* __restrict__ deg, float* __restrict__ dinv, int n) {
    int i = blockIdx.x * blockDim.x + threadIdx.x;
    if (i < n) dinv[i] = rsqrtf((float)deg[i] + 1.0f);   // +1 self-loop
}

// single-block exclusive scan of deg[n] -> off[n+1]; also zeros cursor[]
__global__ __launch_bounds__(1024) void scan_offsets(
    const int* __restrict__ deg, int* __restrict__ off, int* __restrict__ cursor, int n)
{
    __shared__ int carry;
    __shared__ int tmp[1024];
    if (threadIdx.x == 0) carry = 0;
    __syncthreads();
    for (int base = 0; base < n; base += 1024) {
        int i = base + (int)threadIdx.x;
        int v = (i < n) ? deg[i] : 0;
        tmp[threadIdx.x] = v;
        __syncthreads();
        for (int o = 1; o < 1024; o <<= 1) {
            int t = (threadIdx.x >= o) ? tmp[threadIdx.x - o] : 0;
            __syncthreads();
            tmp[threadIdx.x] += t;
            __syncthreads();
        }
        if (i < n) {
            off[i] = carry + tmp[threadIdx.x] - v;   // exclusive
            cursor[i] = 0;
        }
        __syncthreads();
        if (threadIdx.x == 0) carry += tmp[1023];
        __syncthreads();
    }
    if (threadIdx.x == 0) off[n] = carry;
}

// bucket-fill CSR: csrc[p] = src, cen[p] = dinv[src]*dinv[dst]
__global__ void fill_csr(const int* __restrict__ src, const int* __restrict__ dst,
                         const float* __restrict__ dinv, const int* __restrict__ off,
                         int* __restrict__ cursor, int* __restrict__ csrc,
                         float* __restrict__ cen, int E)
{
    int i = blockIdx.x * blockDim.x + threadIdx.x;
    int stride = gridDim.x * blockDim.x;
    for (; i < E; i += stride) {
        int s = src[i], d = dst[i];
        int p = off[d] + atomicAdd(&cursor[d], 1);
        csrc[p] = s;
        cen[p]  = dinv[s] * dinv[d];
    }
}

// ---------------- GEMM: out[N,128] = (relu_in? relu(in) : in)[N,128] @ W[128,128] (+bias) ----------------

__global__ __launch_bounds__(256) void gemm128(
    const float* __restrict__ in, const float* __restrict__ W,
    const float* __restrict__ bias, float* __restrict__ out,
    int n_rows, int relu_in, int relu_out)
{
    __shared__ float Wl[128 * 128];
    for (int i = threadIdx.x; i < 128 * 128; i += 256) Wl[i] = W[i];
    __syncthreads();

    int lane = threadIdx.x & 63;
    int wid  = (blockIdx.x * 256 + threadIdx.x) >> 6;
    int nw   = (gridDim.x * 256) >> 6;

    float bb0 = 0.f, bb1 = 0.f;
    if (bias) { bb0 = bias[lane]; bb1 = bias[lane + 64]; }

    for (int row = wid; row < n_rows; row += nw) {
        const float* xr = in + (size_t)row * 128;
        float a0 = bb0, a1 = bb1;
        #pragma unroll
        for (int k = 0; k < 128; k += 4) {
            float4 xv = *(const float4*)(xr + k);
            if (relu_in) {
                xv.x = fmaxf(xv.x, 0.f); xv.y = fmaxf(xv.y, 0.f);
                xv.z = fmaxf(xv.z, 0.f); xv.w = fmaxf(xv.w, 0.f);
            }
            a0 = fmaf(xv.x, Wl[(k + 0) * 128 + lane], a0);
            a1 = fmaf(xv.x, Wl[(k + 0) * 128 + 64 + lane], a1);
            a0 = fmaf(xv.y, Wl[(k + 1) * 128 + lane], a0);
            a1 = fmaf(xv.y, Wl[(k + 1) * 128 + 64 + lane], a1);
            a0 = fmaf(xv.z, Wl[(k + 2) * 128 + lane], a0);
            a1 = fmaf(xv.z, Wl[(k + 2) * 128 + 64 + lane], a1);
            a0 = fmaf(xv.w, Wl[(k + 3) * 128 + lane], a0);
            a1 = fmaf(xv.w, Wl[(k + 3) * 128 + 64 + lane], a1);
        }
        if (relu_out) { a0 = fmaxf(a0, 0.f); a1 = fmaxf(a1, 0.f); }
        out[(size_t)row * 128 + lane]      = a0;
        out[(size_t)row * 128 + 64 + lane] = a1;
    }
}

// ---------------- CSR gather aggregation ----------------
// agg[n] = b + hW[n]*dinv[n]^2 + sum_{e in CSR[n]} hW[csrc[e]] * cen[e]
// One wave per node; lane handles features {lane, lane+64}. No atomics.

__global__ __launch_bounds__(256) void gather_agg(
    const float* __restrict__ hW, const int* __restrict__ csrc,
    const float* __restrict__ cen, const int* __restrict__ off,
    const float* __restrict__ dinv, const float* __restrict__ bias,
    float* __restrict__ out, int n)
{
    int lane = threadIdx.x & 63;
    int wid  = (blockIdx.x * 256 + threadIdx.x) >> 6;
    int nw   = (gridDim.x * 256) >> 6;

    float bb0 = bias[lane], bb1 = bias[lane + 64];

    for (int node = wid; node < n; node += nw) {
        float sn = dinv[node]; sn *= sn;
        const float* hr = hW + (size_t)node * 128;
        float a0 = fmaf(hr[lane],      sn, bb0);
        float a1 = fmaf(hr[lane + 64], sn, bb1);
        int e0 = off[node], e1 = off[node + 1];
        for (int e = e0; e < e1; e++) {
            int s   = csrc[e];
            float w = cen[e];
            const float* hs = hW + (size_t)s * 128;
            a0 = fmaf(hs[lane],      w, a0);
            a1 = fmaf(hs[lane + 64], w, a1);
        }
        out[(size_t)node * 128 + lane]      = a0;
        out[(size_t)node * 128 + 64 + lane] = a1;
    }
}

// ---------------- out = log_softmax( h[N,128] @ W[128,40] + b ) ----------------

__global__ __launch_bounds__(256) void lin2_lsm(
    const float* __restrict__ h, const float* __restrict__ W,
    const float* __restrict__ bias, float* __restrict__ out, int n)
{
    __shared__ float Wl[128 * 40];
    for (int i = threadIdx.x; i < 128 * 40; i += 256) Wl[i] = W[i];
    __syncthreads();

    int lane = threadIdx.x & 63;
    int wid  = (blockIdx.x * 256 + threadIdx.x) >> 6;
    int nw   = (gridDim.x * 256) >> 6;

    for (int row = wid; row < n; row += nw) {
        const float* xr = h + (size_t)row * 128;
        float acc = -INFINITY;
        if (lane < 40) {
            acc = bias[lane];
            for (int k = 0; k < 128; k++)
                acc = fmaf(xr[k], Wl[k * 40 + lane], acc);
        }
        float m = acc;
        #pragma unroll
        for (int off2 = 32; off2 >= 1; off2 >>= 1)
            m = fmaxf(m, __shfl_xor(m, off2, 64));
        float ex = (lane < 40) ? __expf(acc - m) : 0.f;
        float s = ex;
        #pragma unroll
        for (int off2 = 32; off2 >= 1; off2 >>= 1)
            s += __shfl_xor(s, off2, 64);
        float ls = __logf(s);
        if (lane < 40) out[(size_t)row * 40 + lane] = acc - m - ls;
    }
}

// ---------------- launch ----------------

extern "C" void kernel_launch(void* const* d_in, const int* in_sizes, int n_in,
                              void* d_out, int out_size, void* d_ws, size_t ws_size,
                              hipStream_t stream)
{
    const float* x   = (const float*)d_in[0];
    const int*   ei  = (const int*)d_in[1];
    const float* W1  = (const float*)d_in[2];  const float* b1  = (const float*)d_in[3];
    const float* W2  = (const float*)d_in[4];  const float* b2  = (const float*)d_in[5];
    const float* W3  = (const float*)d_in[6];  const float* b3  = (const float*)d_in[7];
    const float* l1w = (const float*)d_in[8];  const float* l1b = (const float*)d_in[9];
    const float* l2w = (const float*)d_in[10]; const float* l2b = (const float*)d_in[11];

    const int N = in_sizes[0] / 128;
    const int E = in_sizes[1] / 2;
    const int* src = ei;
    const int* dst = ei + E;

    // workspace layout (bytes): all 4-byte elements
    char* wsb = (char*)d_ws;
    int*   deg    = (int*)wsb;                    wsb += (size_t)N * 4;       // reused as cursor
    int*   off    = (int*)wsb;                    wsb += (size_t)(N + 1) * 4;
    int*   csrc   = (int*)wsb;                    wsb += (size_t)E * 4;
    float* cen    = (float*)wsb;                  wsb += (size_t)E * 4;
    float* dinv   = (float*)wsb;                  wsb += (size_t)N * 4;
    float* bufH   = (float*)wsb;                  wsb += (size_t)N * 128 * 4;
    float* bufA   = (float*)wsb;

    float* outp = (float*)d_out;

    // ---- CSR build (once) ----
    zero_i32<<<(N + 255) / 256, 256, 0, stream>>>(deg, N);
    count_deg<<<2048, 256, 0, stream>>>(dst, deg, E);
    finalize_dinv<<<(N + 255) / 256, 256, 0, stream>>>(deg, dinv, N);
    scan_offsets<<<1, 1024, 0, stream>>>(deg, off, deg /*cursor, reuse*/, N);
    fill_csr<<<2048, 256, 0, stream>>>(src, dst, dinv, off, deg, csrc, cen, E);

    // ---- layer 1 ----
    gemm128<<<2048, 256, 0, stream>>>(x, W1, nullptr, bufH, N, 0, 0);
    gather_agg<<<4096, 256, 0, stream>>>(bufH, csrc, cen, off, dinv, b1, bufA, N);

    // ---- layer 2 ----
    gemm128<<<2048, 256, 0, stream>>>(bufA, W2, nullptr, bufH, N, 1, 0);
    gather_agg<<<4096, 256, 0, stream>>>(bufH, csrc, cen, off, dinv, b2, bufA, N);

    // ---- layer 3 ----
    gemm128<<<2048, 256, 0, stream>>>(bufA, W3, nullptr, bufH, N, 1, 0);
    gather_agg<<<4096, 256, 0, stream>>>(bufH, csrc, cen, off, dinv, b3, bufA, N);

    // ---- lin1 (+relu both sides) ----
    gemm128<<<2048, 256, 0, stream>>>(bufA, l1w, l1b, bufH, N, 1, 1);

    // ---- lin2 + log_softmax ----
    lin2_lsm<<<2048, 256, 0, stream>>>(bufH, l2w, l2b, outp, N);
}

// Round 3
// 1117.531 us; speedup vs baseline: 8.6242x; 2.2845x over previous
//
#include <hip/hip_runtime.h>
#include <math.h>

typedef __bf16 bf16;
typedef bf16  bf16x8 __attribute__((ext_vector_type(8)));
typedef bf16  bf16x4 __attribute__((ext_vector_type(4)));
typedef float f32x4  __attribute__((ext_vector_type(4)));

// ---------------- degree / norm precompute ----------------

__global__ void zero_i32(int* __restrict__ p, int n) {
    int i = blockIdx.x * blockDim.x + threadIdx.x;
    if (i < n) p[i] = 0;
}

__global__ void count_deg(const int* __restrict__ dst, int* __restrict__ deg, int E) {
    int i = blockIdx.x * blockDim.x + threadIdx.x;
    int stride = gridDim.x * blockDim.x;
    for (; i < E; i += stride) atomicAdd(&deg[dst[i]], 1);
}

__global__ void finalize_dinv(const int* __restrict__ deg, float* __restrict__ dinv, int n) {
    int i = blockIdx.x * blockDim.x + threadIdx.x;
    if (i < n) dinv[i] = rsqrtf((float)deg[i] + 1.0f);   // +1 self-loop
}

// single-block exclusive scan of deg[n] -> off[n+1]; also zeros cursor[]
__global__ __launch_bounds__(1024) void scan_offsets(
    const int* __restrict__ deg, int* __restrict__ off, int* __restrict__ cursor, int n)
{
    __shared__ int carry;
    __shared__ int tmp[1024];
    if (threadIdx.x == 0) carry = 0;
    __syncthreads();
    for (int base = 0; base < n; base += 1024) {
        int i = base + (int)threadIdx.x;
        int v = (i < n) ? deg[i] : 0;
        tmp[threadIdx.x] = v;
        __syncthreads();
        for (int o = 1; o < 1024; o <<= 1) {
            int t = (threadIdx.x >= o) ? tmp[threadIdx.x - o] : 0;
            __syncthreads();
            tmp[threadIdx.x] += t;
            __syncthreads();
        }
        if (i < n) {
            off[i] = carry + tmp[threadIdx.x] - v;   // exclusive
            cursor[i] = 0;
        }
        __syncthreads();
        if (threadIdx.x == 0) carry += tmp[1023];
        __syncthreads();
    }
    if (threadIdx.x == 0) off[n] = carry;
}

// bucket-fill CSR: csrc[p] = src, cen[p] = dinv[src]*dinv[dst]
__global__ void fill_csr(const int* __restrict__ src, const int* __restrict__ dst,
                         const float* __restrict__ dinv, const int* __restrict__ off,
                         int* __restrict__ cursor, int* __restrict__ csrc,
                         float* __restrict__ cen, int E)
{
    int i = blockIdx.x * blockDim.x + threadIdx.x;
    int stride = gridDim.x * blockDim.x;
    for (; i < E; i += stride) {
        int s = src[i], d = dst[i];
        int p = off[d] + atomicAdd(&cursor[d], 1);
        csrc[p] = s;
        cen[p]  = dinv[s] * dinv[d];
    }
}

// ---------------- fp32 -> split bf16 (hi/lo), optional relu ----------------

__global__ __launch_bounds__(256) void split_relu(
    const float* __restrict__ in, bf16* __restrict__ hi, bf16* __restrict__ lo,
    long long n4, int do_relu)
{
    long long i = (long long)blockIdx.x * blockDim.x + threadIdx.x;
    long long stride = (long long)gridDim.x * blockDim.x;
    for (; i < n4; i += stride) {
        float4 v = *(const float4*)(in + i * 4);
        if (do_relu) {
            v.x = fmaxf(v.x, 0.f); v.y = fmaxf(v.y, 0.f);
            v.z = fmaxf(v.z, 0.f); v.w = fmaxf(v.w, 0.f);
        }
        bf16x4 h, l;
        h[0] = (bf16)v.x; l[0] = (bf16)(v.x - (float)h[0]);
        h[1] = (bf16)v.y; l[1] = (bf16)(v.y - (float)h[1]);
        h[2] = (bf16)v.z; l[2] = (bf16)(v.z - (float)h[2]);
        h[3] = (bf16)v.w; l[3] = (bf16)(v.w - (float)h[3]);
        *(bf16x4*)(hi + i * 4) = h;
        *(bf16x4*)(lo + i * 4) = l;
    }
}

// ---------------- MFMA GEMM: out[N,128] = (Ahi+Alo)[N,128] @ W[128,128] (+bias, relu) ----------------
// Split-bf16 3-term: A*B ~= Ahi*Bhi + Ahi*Blo + Alo*Bhi, fp32 accumulate.
// Block = 4 waves; wave w owns cols [32w,32w+32); W frags in registers; grid-stride row tiles.

__global__ __launch_bounds__(256) void gemm_mfma(
    const bf16* __restrict__ ahi, const bf16* __restrict__ alo,
    const float* __restrict__ W, const float* __restrict__ bias,
    float* __restrict__ out, int n_rows, int relu_out)
{
    const int lane = threadIdx.x & 63;
    const int wv   = threadIdx.x >> 6;      // wave in block
    const int col0 = wv * 32;
    const int l15  = lane & 15;
    const int lg   = lane >> 4;

    // B fragments (registers): bhi/blo[tile][kstep], lane holds W[ks*32+lg*8+j][col]
    bf16x8 bhi[2][4], blo[2][4];
    #pragma unroll
    for (int t = 0; t < 2; t++) {
        int c = col0 + 16 * t + l15;
        #pragma unroll
        for (int ks = 0; ks < 4; ks++) {
            #pragma unroll
            for (int j = 0; j < 8; j++) {
                float wvv = W[(ks * 32 + lg * 8 + j) * 128 + c];
                bf16 h = (bf16)wvv;
                bhi[t][ks][j] = h;
                blo[t][ks][j] = (bf16)(wvv - (float)h);
            }
        }
    }

    const int nrt = n_rows >> 4;   // row tiles of 16
    for (int rt = blockIdx.x; rt < nrt; rt += gridDim.x) {
        const int row = rt * 16 + l15;
        const bf16* pah = ahi + (size_t)row * 128 + lg * 8;
        const bf16* pal = alo + (size_t)row * 128 + lg * 8;
        bf16x8 Ah[4], Al[4];
        #pragma unroll
        for (int ks = 0; ks < 4; ks++) {
            Ah[ks] = *(const bf16x8*)(pah + ks * 32);
            Al[ks] = *(const bf16x8*)(pal + ks * 32);
        }
        #pragma unroll
        for (int t = 0; t < 2; t++) {
            f32x4 acc = {0.f, 0.f, 0.f, 0.f};
            #pragma unroll
            for (int ks = 0; ks < 4; ks++) {
                acc = __builtin_amdgcn_mfma_f32_16x16x32_bf16(Al[ks], bhi[t][ks], acc, 0, 0, 0);
                acc = __builtin_amdgcn_mfma_f32_16x16x32_bf16(Ah[ks], blo[t][ks], acc, 0, 0, 0);
                acc = __builtin_amdgcn_mfma_f32_16x16x32_bf16(Ah[ks], bhi[t][ks], acc, 0, 0, 0);
            }
            const int c = col0 + 16 * t + l15;
            const float bv = bias ? bias[c] : 0.f;
            #pragma unroll
            for (int r = 0; r < 4; r++) {
                float v = acc[r] + bv;
                if (relu_out) v = fmaxf(v, 0.f);
                out[(size_t)(rt * 16 + lg * 4 + r) * 128 + c] = v;
            }
        }
    }
}

// ---------------- CSR gather aggregation + relu + bf16 split epilogue ----------------
// a[n] = b + hW[n]*dinv[n]^2 + sum_{e} hW[csrc[e]] * cen[e];  out = split(relu(a))

__global__ __launch_bounds__(256) void gather_agg_split(
    const float* __restrict__ hW, const int* __restrict__ csrc,
    const float* __restrict__ cen, const int* __restrict__ off,
    const float* __restrict__ dinv, const float* __restrict__ bias,
    bf16* __restrict__ ohi, bf16* __restrict__ olo, int n)
{
    int lane = threadIdx.x & 63;
    int wid  = (blockIdx.x * 256 + threadIdx.x) >> 6;
    int nw   = (gridDim.x * 256) >> 6;

    float bb0 = bias[lane], bb1 = bias[lane + 64];

    for (int node = wid; node < n; node += nw) {
        float sn = dinv[node]; sn *= sn;
        const float* hr = hW + (size_t)node * 128;
        float a0 = fmaf(hr[lane],      sn, bb0);
        float a1 = fmaf(hr[lane + 64], sn, bb1);
        int e0 = off[node], e1 = off[node + 1];
        for (int e = e0; e < e1; e++) {
            int s   = csrc[e];
            float w = cen[e];
            const float* hs = hW + (size_t)s * 128;
            a0 = fmaf(hs[lane],      w, a0);
            a1 = fmaf(hs[lane + 64], w, a1);
        }
        a0 = fmaxf(a0, 0.f);
        a1 = fmaxf(a1, 0.f);
        bf16 h0 = (bf16)a0, h1 = (bf16)a1;
        ohi[(size_t)node * 128 + lane]      = h0;
        ohi[(size_t)node * 128 + 64 + lane] = h1;
        olo[(size_t)node * 128 + lane]      = (bf16)(a0 - (float)h0);
        olo[(size_t)node * 128 + 64 + lane] = (bf16)(a1 - (float)h1);
    }
}

// ---------------- out = log_softmax( h[N,128] @ W[128,40] + b ) ----------------

__global__ __launch_bounds__(256) void lin2_lsm(
    const float* __restrict__ h, const float* __restrict__ W,
    const float* __restrict__ bias, float* __restrict__ out, int n)
{
    __shared__ float Wl[128 * 40];
    for (int i = threadIdx.x; i < 128 * 40; i += 256) Wl[i] = W[i];
    __syncthreads();

    int lane = threadIdx.x & 63;
    int wid  = (blockIdx.x * 256 + threadIdx.x) >> 6;
    int nw   = (gridDim.x * 256) >> 6;

    for (int row = wid; row < n; row += nw) {
        const float* xr = h + (size_t)row * 128;
        float acc = -INFINITY;
        if (lane < 40) {
            acc = bias[lane];
            for (int k = 0; k < 128; k++)
                acc = fmaf(xr[k], Wl[k * 40 + lane], acc);
        }
        float m = acc;
        #pragma unroll
        for (int off2 = 32; off2 >= 1; off2 >>= 1)
            m = fmaxf(m, __shfl_xor(m, off2, 64));
        float ex = (lane < 40) ? __expf(acc - m) : 0.f;
        float s = ex;
        #pragma unroll
        for (int off2 = 32; off2 >= 1; off2 >>= 1)
            s += __shfl_xor(s, off2, 64);
        float ls = __logf(s);
        if (lane < 40) out[(size_t)row * 40 + lane] = acc - m - ls;
    }
}

// ---------------- launch ----------------

static inline size_t align256(size_t x) { return (x + 255) & ~(size_t)255; }

extern "C" void kernel_launch(void* const* d_in, const int* in_sizes, int n_in,
                              void* d_out, int out_size, void* d_ws, size_t ws_size,
                              hipStream_t stream)
{
    const float* x   = (const float*)d_in[0];
    const int*   ei  = (const int*)d_in[1];
    const float* W1  = (const float*)d_in[2];  const float* b1  = (const float*)d_in[3];
    const float* W2  = (const float*)d_in[4];  const float* b2  = (const float*)d_in[5];
    const float* W3  = (const float*)d_in[6];  const float* b3  = (const float*)d_in[7];
    const float* l1w = (const float*)d_in[8];  const float* l1b = (const float*)d_in[9];
    const float* l2w = (const float*)d_in[10]; const float* l2b = (const float*)d_in[11];

    const int N = in_sizes[0] / 128;
    const int E = in_sizes[1] / 2;
    const int* src = ei;
    const int* dst = ei + E;

    // workspace layout, 256B-aligned regions
    char* wsb = (char*)d_ws;
    size_t o = 0;
    int*   deg  = (int*)(wsb + o);   o = align256(o + (size_t)N * 4);        // reused as cursor
    int*   off  = (int*)(wsb + o);   o = align256(o + (size_t)(N + 1) * 4);
    int*   csrc = (int*)(wsb + o);   o = align256(o + (size_t)E * 4);
    float* cen  = (float*)(wsb + o); o = align256(o + (size_t)E * 4);
    float* dinv = (float*)(wsb + o); o = align256(o + (size_t)N * 4);
    float* bufH = (float*)(wsb + o); o = align256(o + (size_t)N * 128 * 4);
    bf16*  ahi  = (bf16*)(wsb + o);  o = align256(o + (size_t)N * 128 * 2);
    bf16*  alo  = (bf16*)(wsb + o);  o = align256(o + (size_t)N * 128 * 2);

    float* outp = (float*)d_out;

    // ---- CSR build (once) ----
    zero_i32<<<(N + 255) / 256, 256, 0, stream>>>(deg, N);
    count_deg<<<2048, 256, 0, stream>>>(dst, deg, E);
    finalize_dinv<<<(N + 255) / 256, 256, 0, stream>>>(deg, dinv, N);
    scan_offsets<<<1, 1024, 0, stream>>>(deg, off, deg /*cursor, reuse*/, N);
    fill_csr<<<2048, 256, 0, stream>>>(src, dst, dinv, off, deg, csrc, cen, E);

    // ---- split x ----
    split_relu<<<4096, 256, 0, stream>>>(x, ahi, alo, (long long)N * 32, 0);

    // ---- layer 1 ----
    gemm_mfma<<<2048, 256, 0, stream>>>(ahi, alo, W1, nullptr, bufH, N, 0);
    gather_agg_split<<<4096, 256, 0, stream>>>(bufH, csrc, cen, off, dinv, b1, ahi, alo, N);

    // ---- layer 2 ----
    gemm_mfma<<<2048, 256, 0, stream>>>(ahi, alo, W2, nullptr, bufH, N, 0);
    gather_agg_split<<<4096, 256, 0, stream>>>(bufH, csrc, cen, off, dinv, b2, ahi, alo, N);

    // ---- layer 3 ----
    gemm_mfma<<<2048, 256, 0, stream>>>(ahi, alo, W3, nullptr, bufH, N, 0);
    gather_agg_split<<<4096, 256, 0, stream>>>(bufH, csrc, cen, off, dinv, b3, ahi, alo, N);

    // ---- lin1 (+bias+relu) ----
    gemm_mfma<<<2048, 256, 0, stream>>>(ahi, alo, l1w, l1b, bufH, N, 1);

    // ---- lin2 + log_softmax ----
    lin2_lsm<<<2048, 256, 0, stream>>>(bufH, l2w, l2b, outp, N);
}

// Round 4
// 933.661 us; speedup vs baseline: 10.3226x; 1.1969x over previous
//
#include <hip/hip_runtime.h>
#include <math.h>

typedef __bf16 bf16;
typedef bf16  bf16x8 __attribute__((ext_vector_type(8)));
typedef bf16  bf16x4 __attribute__((ext_vector_type(4)));
typedef float f32x4  __attribute__((ext_vector_type(4)));

// ---------------- degree / norm precompute ----------------

__global__ void zero_i32(int* __restrict__ p, int n) {
    int i = blockIdx.x * blockDim.x + threadIdx.x;
    if (i < n) p[i] = 0;
}

__global__ void count_deg(const int* __restrict__ dst, int* __restrict__ deg, int E) {
    int i = blockIdx.x * blockDim.x + threadIdx.x;
    int stride = gridDim.x * blockDim.x;
    for (; i < E; i += stride) atomicAdd(&deg[dst[i]], 1);
}

__global__ void finalize_dinv(const int* __restrict__ deg, float* __restrict__ dinv, int n) {
    int i = blockIdx.x * blockDim.x + threadIdx.x;
    if (i < n) dinv[i] = rsqrtf((float)deg[i] + 1.0f);   // +1 self-loop
}

// ---------------- parallel 3-phase exclusive scan ----------------
#define SCHUNK 2048

__global__ __launch_bounds__(256) void scan_p1(const int* __restrict__ deg,
                                               int* __restrict__ bsum, int n) {
    int base = blockIdx.x * SCHUNK;
    int s = 0;
    for (int i = threadIdx.x; i < SCHUNK; i += 256) {
        int idx = base + i;
        s += (idx < n) ? deg[idx] : 0;
    }
    #pragma unroll
    for (int o = 32; o >= 1; o >>= 1) s += __shfl_xor(s, o, 64);
    __shared__ int ws[4];
    if ((threadIdx.x & 63) == 0) ws[threadIdx.x >> 6] = s;
    __syncthreads();
    if (threadIdx.x == 0) bsum[blockIdx.x] = ws[0] + ws[1] + ws[2] + ws[3];
}

// single wave: exclusive-scan bsum[nb] in place; writes off[n] = total
__global__ __launch_bounds__(64) void scan_p2(int* __restrict__ bsum,
                                              int* __restrict__ off, int nb, int n) {
    int lane = threadIdx.x;
    __shared__ int carry_s;
    if (lane == 0) carry_s = 0;
    __syncthreads();
    for (int base = 0; base < nb; base += 64) {
        int i = base + lane;
        int v = (i < nb) ? bsum[i] : 0;
        int x = v;
        #pragma unroll
        for (int o = 1; o < 64; o <<= 1) {
            int t = __shfl_up(x, o, 64);
            if (lane >= o) x += t;
        }
        int carry = carry_s;
        if (i < nb) bsum[i] = carry + x - v;   // exclusive
        int total = __shfl(x, 63, 64);
        __syncthreads();
        if (lane == 0) carry_s = carry + total;
        __syncthreads();
    }
    if (lane == 0) off[n] = carry_s;
}

__global__ __launch_bounds__(256) void scan_p3(const int* __restrict__ deg,
                                               const int* __restrict__ bsum,
                                               int* __restrict__ off,
                                               int* __restrict__ cursor, int n) {
    int base = blockIdx.x * SCHUNK + (int)threadIdx.x * 8;
    int v[8]; int s = 0;
    #pragma unroll
    for (int j = 0; j < 8; j++) {
        int idx = base + j;
        v[j] = (idx < n) ? deg[idx] : 0;
        s += v[j];
    }
    int lane = threadIdx.x & 63, wv = threadIdx.x >> 6;
    int x = s;
    #pragma unroll
    for (int o = 1; o < 64; o <<= 1) {
        int t = __shfl_up(x, o, 64);
        if (lane >= o) x += t;
    }
    __shared__ int wsum[4];
    if (lane == 63) wsum[wv] = x;
    __syncthreads();
    int wbase = 0;
    #pragma unroll
    for (int w = 0; w < 4; w++) if (w < wv) wbase += wsum[w];
    int tbase = bsum[blockIdx.x] + wbase + x - s;   // exclusive prefix for this thread
    #pragma unroll
    for (int j = 0; j < 8; j++) {
        int idx = base + j;
        if (idx < n) { off[idx] = tbase; cursor[idx] = 0; tbase += v[j]; }
    }
}

// bucket-fill CSR: csrc[p] = src, cen[p] = dinv[src]*dinv[dst]
__global__ void fill_csr(const int* __restrict__ src, const int* __restrict__ dst,
                         const float* __restrict__ dinv, const int* __restrict__ off,
                         int* __restrict__ cursor, int* __restrict__ csrc,
                         float* __restrict__ cen, int E)
{
    int i = blockIdx.x * blockDim.x + threadIdx.x;
    int stride = gridDim.x * blockDim.x;
    for (; i < E; i += stride) {
        int s = src[i], d = dst[i];
        int p = off[d] + atomicAdd(&cursor[d], 1);
        csrc[p] = s;
        cen[p]  = dinv[s] * dinv[d];
    }
}

// ---------------- fp32 -> split bf16 (hi/lo) ----------------

__global__ __launch_bounds__(256) void split_relu(
    const float* __restrict__ in, bf16* __restrict__ hi, bf16* __restrict__ lo,
    long long n4, int do_relu)
{
    long long i = (long long)blockIdx.x * blockDim.x + threadIdx.x;
    long long stride = (long long)gridDim.x * blockDim.x;
    for (; i < n4; i += stride) {
        float4 v = *(const float4*)(in + i * 4);
        if (do_relu) {
            v.x = fmaxf(v.x, 0.f); v.y = fmaxf(v.y, 0.f);
            v.z = fmaxf(v.z, 0.f); v.w = fmaxf(v.w, 0.f);
        }
        bf16x4 h, l;
        h[0] = (bf16)v.x; l[0] = (bf16)(v.x - (float)h[0]);
        h[1] = (bf16)v.y; l[1] = (bf16)(v.y - (float)h[1]);
        h[2] = (bf16)v.z; l[2] = (bf16)(v.z - (float)h[2]);
        h[3] = (bf16)v.w; l[3] = (bf16)(v.w - (float)h[3]);
        *(bf16x4*)(hi + i * 4) = h;
        *(bf16x4*)(lo + i * 4) = l;
    }
}

// ---------------- MFMA GEMM: (Ahi+Alo)[N,128] @ W[128,128] (+bias,+relu) -> split bf16 ----------------

__global__ __launch_bounds__(256) void gemm_mfma(
    const bf16* __restrict__ ahi, const bf16* __restrict__ alo,
    const float* __restrict__ W, const float* __restrict__ bias,
    bf16* __restrict__ ohi, bf16* __restrict__ olo, int n_rows, int relu_out)
{
    const int lane = threadIdx.x & 63;
    const int wv   = threadIdx.x >> 6;
    const int col0 = wv * 32;
    const int l15  = lane & 15;
    const int lg   = lane >> 4;

    bf16x8 bhi[2][4], blo[2][4];
    #pragma unroll
    for (int t = 0; t < 2; t++) {
        int c = col0 + 16 * t + l15;
        #pragma unroll
        for (int ks = 0; ks < 4; ks++) {
            #pragma unroll
            for (int j = 0; j < 8; j++) {
                float wvv = W[(ks * 32 + lg * 8 + j) * 128 + c];
                bf16 h = (bf16)wvv;
                bhi[t][ks][j] = h;
                blo[t][ks][j] = (bf16)(wvv - (float)h);
            }
        }
    }

    const int nrt = n_rows >> 4;
    for (int rt = blockIdx.x; rt < nrt; rt += gridDim.x) {
        const int row = rt * 16 + l15;
        const bf16* pah = ahi + (size_t)row * 128 + lg * 8;
        const bf16* pal = alo + (size_t)row * 128 + lg * 8;
        bf16x8 Ah[4], Al[4];
        #pragma unroll
        for (int ks = 0; ks < 4; ks++) {
            Ah[ks] = *(const bf16x8*)(pah + ks * 32);
            Al[ks] = *(const bf16x8*)(pal + ks * 32);
        }
        #pragma unroll
        for (int t = 0; t < 2; t++) {
            f32x4 acc = {0.f, 0.f, 0.f, 0.f};
            #pragma unroll
            for (int ks = 0; ks < 4; ks++) {
                acc = __builtin_amdgcn_mfma_f32_16x16x32_bf16(Al[ks], bhi[t][ks], acc, 0, 0, 0);
                acc = __builtin_amdgcn_mfma_f32_16x16x32_bf16(Ah[ks], blo[t][ks], acc, 0, 0, 0);
                acc = __builtin_amdgcn_mfma_f32_16x16x32_bf16(Ah[ks], bhi[t][ks], acc, 0, 0, 0);
            }
            const int c = col0 + 16 * t + l15;
            const float bv = bias ? bias[c] : 0.f;
            #pragma unroll
            for (int r = 0; r < 4; r++) {
                float v = acc[r] + bv;
                if (relu_out) v = fmaxf(v, 0.f);
                size_t idx = (size_t)(rt * 16 + lg * 4 + r) * 128 + c;
                bf16 h = (bf16)v;
                ohi[idx] = h;
                olo[idx] = (bf16)(v - (float)h);
            }
        }
    }
}

// ---------------- CSR gather aggregation (bf16 messages) + relu + split epilogue ----------------
// a[n] = b + (hhi+hlo)[n]*dinv[n]^2 + sum_e hhi[csrc[e]] * cen[e];  out = split(relu(a))

__global__ __launch_bounds__(256) void gather_agg_split(
    const bf16* __restrict__ hhi, const bf16* __restrict__ hlo,
    const int* __restrict__ csrc, const float* __restrict__ cen,
    const int* __restrict__ off, const float* __restrict__ dinv,
    const float* __restrict__ bias,
    bf16* __restrict__ ohi, bf16* __restrict__ olo, int n)
{
    int lane = threadIdx.x & 63;
    int wid  = (blockIdx.x * 256 + threadIdx.x) >> 6;
    int nw   = (gridDim.x * 256) >> 6;

    float bb0 = bias[lane], bb1 = bias[lane + 64];

    for (int node = wid; node < n; node += nw) {
        float sn = dinv[node]; sn *= sn;
        size_t nb = (size_t)node * 128;
        float h0 = (float)hhi[nb + lane]      + (float)hlo[nb + lane];
        float h1 = (float)hhi[nb + 64 + lane] + (float)hlo[nb + 64 + lane];
        float a0 = fmaf(h0, sn, bb0);
        float a1 = fmaf(h1, sn, bb1);
        int e0 = off[node], e1 = off[node + 1];
        for (int e = e0; e < e1; e++) {
            int s   = csrc[e];
            float w = cen[e];
            size_t sb = (size_t)s * 128;
            a0 = fmaf((float)hhi[sb + lane],      w, a0);
            a1 = fmaf((float)hhi[sb + 64 + lane], w, a1);
        }
        a0 = fmaxf(a0, 0.f);
        a1 = fmaxf(a1, 0.f);
        bf16 o0 = (bf16)a0, o1 = (bf16)a1;
        ohi[nb + lane]      = o0;
        ohi[nb + 64 + lane] = o1;
        olo[nb + lane]      = (bf16)(a0 - (float)o0);
        olo[nb + 64 + lane] = (bf16)(a1 - (float)o1);
    }
}

// ---------------- out = log_softmax( (hhi+hlo)[N,128] @ W[128,40] + b ) ----------------

__global__ __launch_bounds__(256) void lin2_lsm(
    const bf16* __restrict__ hhi, const bf16* __restrict__ hlo,
    const float* __restrict__ W, const float* __restrict__ bias,
    float* __restrict__ out, int n)
{
    __shared__ float Wl[128 * 40];
    for (int i = threadIdx.x; i < 128 * 40; i += 256) Wl[i] = W[i];
    __syncthreads();

    int lane = threadIdx.x & 63;
    int wid  = (blockIdx.x * 256 + threadIdx.x) >> 6;
    int nw   = (gridDim.x * 256) >> 6;

    for (int row = wid; row < n; row += nw) {
        const bf16* xh = hhi + (size_t)row * 128;
        const bf16* xl = hlo + (size_t)row * 128;
        float acc = -INFINITY;
        if (lane < 40) {
            acc = bias[lane];
            for (int k = 0; k < 128; k++) {
                float xk = (float)xh[k] + (float)xl[k];
                acc = fmaf(xk, Wl[k * 40 + lane], acc);
            }
        }
        float m = acc;
        #pragma unroll
        for (int off2 = 32; off2 >= 1; off2 >>= 1)
            m = fmaxf(m, __shfl_xor(m, off2, 64));
        float ex = (lane < 40) ? __expf(acc - m) : 0.f;
        float s = ex;
        #pragma unroll
        for (int off2 = 32; off2 >= 1; off2 >>= 1)
            s += __shfl_xor(s, off2, 64);
        float ls = __logf(s);
        if (lane < 40) out[(size_t)row * 40 + lane] = acc - m - ls;
    }
}

// ---------------- launch ----------------

static inline size_t align256(size_t x) { return (x + 255) & ~(size_t)255; }

extern "C" void kernel_launch(void* const* d_in, const int* in_sizes, int n_in,
                              void* d_out, int out_size, void* d_ws, size_t ws_size,
                              hipStream_t stream)
{
    const float* x   = (const float*)d_in[0];
    const int*   ei  = (const int*)d_in[1];
    const float* W1  = (const float*)d_in[2];  const float* b1  = (const float*)d_in[3];
    const float* W2  = (const float*)d_in[4];  const float* b2  = (const float*)d_in[5];
    const float* W3  = (const float*)d_in[6];  const float* b3  = (const float*)d_in[7];
    const float* l1w = (const float*)d_in[8];  const float* l1b = (const float*)d_in[9];
    const float* l2w = (const float*)d_in[10]; const float* l2b = (const float*)d_in[11];

    const int N = in_sizes[0] / 128;
    const int E = in_sizes[1] / 2;
    const int* src = ei;
    const int* dst = ei + E;

    char* wsb = (char*)d_ws;
    size_t o = 0;
    int*   deg  = (int*)(wsb + o);   o = align256(o + (size_t)N * 4);        // reused as cursor
    int*   off  = (int*)(wsb + o);   o = align256(o + (size_t)(N + 1) * 4);
    int*   bsum = (int*)(wsb + o);   o = align256(o + (size_t)4096 * 4);
    int*   csrc = (int*)(wsb + o);   o = align256(o + (size_t)E * 4);
    float* cen  = (float*)(wsb + o); o = align256(o + (size_t)E * 4);
    float* dinv = (float*)(wsb + o); o = align256(o + (size_t)N * 4);
    bf16*  ahi  = (bf16*)(wsb + o);  o = align256(o + (size_t)N * 128 * 2);
    bf16*  alo  = (bf16*)(wsb + o);  o = align256(o + (size_t)N * 128 * 2);
    bf16*  hhi  = (bf16*)(wsb + o);  o = align256(o + (size_t)N * 128 * 2);
    bf16*  hlo  = (bf16*)(wsb + o);  o = align256(o + (size_t)N * 128 * 2);

    float* outp = (float*)d_out;
    const int nb = (N + SCHUNK - 1) / SCHUNK;

    // ---- CSR build (once) ----
    zero_i32<<<(N + 255) / 256, 256, 0, stream>>>(deg, N);
    count_deg<<<2048, 256, 0, stream>>>(dst, deg, E);
    finalize_dinv<<<(N + 255) / 256, 256, 0, stream>>>(deg, dinv, N);
    scan_p1<<<nb, 256, 0, stream>>>(deg, bsum, N);
    scan_p2<<<1, 64, 0, stream>>>(bsum, off, nb, N);
    scan_p3<<<nb, 256, 0, stream>>>(deg, bsum, off, deg /*cursor*/, N);
    fill_csr<<<2048, 256, 0, stream>>>(src, dst, dinv, off, deg, csrc, cen, E);

    // ---- split x ----
    split_relu<<<4096, 256, 0, stream>>>(x, ahi, alo, (long long)N * 32, 0);

    // ---- layer 1 ----
    gemm_mfma<<<2048, 256, 0, stream>>>(ahi, alo, W1, nullptr, hhi, hlo, N, 0);
    gather_agg_split<<<4096, 256, 0, stream>>>(hhi, hlo, csrc, cen, off, dinv, b1, ahi, alo, N);

    // ---- layer 2 ----
    gemm_mfma<<<2048, 256, 0, stream>>>(ahi, alo, W2, nullptr, hhi, hlo, N, 0);
    gather_agg_split<<<4096, 256, 0, stream>>>(hhi, hlo, csrc, cen, off, dinv, b2, ahi, alo, N);

    // ---- layer 3 ----
    gemm_mfma<<<2048, 256, 0, stream>>>(ahi, alo, W3, nullptr, hhi, hlo, N, 0);
    gather_agg_split<<<4096, 256, 0, stream>>>(hhi, hlo, csrc, cen, off, dinv, b3, ahi, alo, N);

    // ---- lin1 (+bias+relu) -> split bf16 ----
    gemm_mfma<<<2048, 256, 0, stream>>>(ahi, alo, l1w, l1b, hhi, hlo, N, 1);

    // ---- lin2 + log_softmax ----
    lin2_lsm<<<2048, 256, 0, stream>>>(hhi, hlo, l2w, l2b, outp, N);
}

// Round 5
// 678.431 us; speedup vs baseline: 14.2060x; 1.3762x over previous
//
#include <hip/hip_runtime.h>
#include <math.h>

typedef __bf16 bf16;
typedef bf16  bf16x8 __attribute__((ext_vector_type(8)));
typedef bf16  bf16x4 __attribute__((ext_vector_type(4)));
typedef bf16  bf16x2 __attribute__((ext_vector_type(2)));
typedef float f32x4  __attribute__((ext_vector_type(4)));

// ---------------- degree / norm precompute ----------------

__global__ void zero_i32(int* __restrict__ p, int n) {
    int i = blockIdx.x * blockDim.x + threadIdx.x;
    if (i < n) p[i] = 0;
}

__global__ void count_deg(const int* __restrict__ dst, int* __restrict__ deg, int E) {
    int i = blockIdx.x * blockDim.x + threadIdx.x;
    int stride = gridDim.x * blockDim.x;
    for (; i < E; i += stride) atomicAdd(&deg[dst[i]], 1);
}

__global__ void finalize_dinv(const int* __restrict__ deg, float* __restrict__ dinv, int n) {
    int i = blockIdx.x * blockDim.x + threadIdx.x;
    if (i < n) dinv[i] = rsqrtf((float)deg[i] + 1.0f);   // +1 self-loop
}

// ---------------- parallel 3-phase exclusive scan ----------------
#define SCHUNK 2048

__global__ __launch_bounds__(256) void scan_p1(const int* __restrict__ deg,
                                               int* __restrict__ bsum, int n) {
    int base = blockIdx.x * SCHUNK;
    int s = 0;
    for (int i = threadIdx.x; i < SCHUNK; i += 256) {
        int idx = base + i;
        s += (idx < n) ? deg[idx] : 0;
    }
    #pragma unroll
    for (int o = 32; o >= 1; o >>= 1) s += __shfl_xor(s, o, 64);
    __shared__ int ws[4];
    if ((threadIdx.x & 63) == 0) ws[threadIdx.x >> 6] = s;
    __syncthreads();
    if (threadIdx.x == 0) bsum[blockIdx.x] = ws[0] + ws[1] + ws[2] + ws[3];
}

// single wave: exclusive-scan bsum[nb] in place; writes off[n] = total
__global__ __launch_bounds__(64) void scan_p2(int* __restrict__ bsum,
                                              int* __restrict__ off, int nb, int n) {
    int lane = threadIdx.x;
    __shared__ int carry_s;
    if (lane == 0) carry_s = 0;
    __syncthreads();
    for (int base = 0; base < nb; base += 64) {
        int i = base + lane;
        int v = (i < nb) ? bsum[i] : 0;
        int x = v;
        #pragma unroll
        for (int o = 1; o < 64; o <<= 1) {
            int t = __shfl_up(x, o, 64);
            if (lane >= o) x += t;
        }
        int carry = carry_s;
        if (i < nb) bsum[i] = carry + x - v;   // exclusive
        int total = __shfl(x, 63, 64);
        __syncthreads();
        if (lane == 0) carry_s = carry + total;
        __syncthreads();
    }
    if (lane == 0) off[n] = carry_s;
}

__global__ __launch_bounds__(256) void scan_p3(const int* __restrict__ deg,
                                               const int* __restrict__ bsum,
                                               int* __restrict__ off,
                                               int* __restrict__ cursor, int n) {
    int base = blockIdx.x * SCHUNK + (int)threadIdx.x * 8;
    int v[8]; int s = 0;
    #pragma unroll
    for (int j = 0; j < 8; j++) {
        int idx = base + j;
        v[j] = (idx < n) ? deg[idx] : 0;
        s += v[j];
    }
    int lane = threadIdx.x & 63, wv = threadIdx.x >> 6;
    int x = s;
    #pragma unroll
    for (int o = 1; o < 64; o <<= 1) {
        int t = __shfl_up(x, o, 64);
        if (lane >= o) x += t;
    }
    __shared__ int wsum[4];
    if (lane == 63) wsum[wv] = x;
    __syncthreads();
    int wbase = 0;
    #pragma unroll
    for (int w = 0; w < 4; w++) if (w < wv) wbase += wsum[w];
    int tbase = bsum[blockIdx.x] + wbase + x - s;   // exclusive prefix for this thread
    #pragma unroll
    for (int j = 0; j < 8; j++) {
        int idx = base + j;
        if (idx < n) { off[idx] = tbase; cursor[idx] = 0; tbase += v[j]; }
    }
}

// bucket-fill CSR: csrc[p] = src, cen[p] = dinv[src]*dinv[dst]
__global__ void fill_csr(const int* __restrict__ src, const int* __restrict__ dst,
                         const float* __restrict__ dinv, const int* __restrict__ off,
                         int* __restrict__ cursor, int* __restrict__ csrc,
                         float* __restrict__ cen, int E)
{
    int i = blockIdx.x * blockDim.x + threadIdx.x;
    int stride = gridDim.x * blockDim.x;
    for (; i < E; i += stride) {
        int s = src[i], d = dst[i];
        int p = off[d] + atomicAdd(&cursor[d], 1);
        csrc[p] = s;
        cen[p]  = dinv[s] * dinv[d];
    }
}

// ---------------- fp32 -> split bf16 (hi/lo) ----------------

__global__ __launch_bounds__(256) void split_relu(
    const float* __restrict__ in, bf16* __restrict__ hi, bf16* __restrict__ lo,
    long long n4, int do_relu)
{
    long long i = (long long)blockIdx.x * blockDim.x + threadIdx.x;
    long long stride = (long long)gridDim.x * blockDim.x;
    for (; i < n4; i += stride) {
        float4 v = *(const float4*)(in + i * 4);
        if (do_relu) {
            v.x = fmaxf(v.x, 0.f); v.y = fmaxf(v.y, 0.f);
            v.z = fmaxf(v.z, 0.f); v.w = fmaxf(v.w, 0.f);
        }
        bf16x4 h, l;
        h[0] = (bf16)v.x; l[0] = (bf16)(v.x - (float)h[0]);
        h[1] = (bf16)v.y; l[1] = (bf16)(v.y - (float)h[1]);
        h[2] = (bf16)v.z; l[2] = (bf16)(v.z - (float)h[2]);
        h[3] = (bf16)v.w; l[3] = (bf16)(v.w - (float)h[3]);
        *(bf16x4*)(hi + i * 4) = h;
        *(bf16x4*)(lo + i * 4) = l;
    }
}

// ---------------- MFMA GEMM: (Ahi+Alo)[N,128] @ W[128,128] (+bias,+relu) -> split bf16 ----------------

__global__ __launch_bounds__(256) void gemm_mfma(
    const bf16* __restrict__ ahi, const bf16* __restrict__ alo,
    const float* __restrict__ W, const float* __restrict__ bias,
    bf16* __restrict__ ohi, bf16* __restrict__ olo, int n_rows, int relu_out)
{
    const int lane = threadIdx.x & 63;
    const int wv   = threadIdx.x >> 6;
    const int col0 = wv * 32;
    const int l15  = lane & 15;
    const int lg   = lane >> 4;

    bf16x8 bhi[2][4], blo[2][4];
    #pragma unroll
    for (int t = 0; t < 2; t++) {
        int c = col0 + 16 * t + l15;
        #pragma unroll
        for (int ks = 0; ks < 4; ks++) {
            #pragma unroll
            for (int j = 0; j < 8; j++) {
                float wvv = W[(ks * 32 + lg * 8 + j) * 128 + c];
                bf16 h = (bf16)wvv;
                bhi[t][ks][j] = h;
                blo[t][ks][j] = (bf16)(wvv - (float)h);
            }
        }
    }

    const int nrt = n_rows >> 4;
    for (int rt = blockIdx.x; rt < nrt; rt += gridDim.x) {
        const int row = rt * 16 + l15;
        const bf16* pah = ahi + (size_t)row * 128 + lg * 8;
        const bf16* pal = alo + (size_t)row * 128 + lg * 8;
        bf16x8 Ah[4], Al[4];
        #pragma unroll
        for (int ks = 0; ks < 4; ks++) {
            Ah[ks] = *(const bf16x8*)(pah + ks * 32);
            Al[ks] = *(const bf16x8*)(pal + ks * 32);
        }
        #pragma unroll
        for (int t = 0; t < 2; t++) {
            f32x4 acc = {0.f, 0.f, 0.f, 0.f};
            #pragma unroll
            for (int ks = 0; ks < 4; ks++) {
                acc = __builtin_amdgcn_mfma_f32_16x16x32_bf16(Al[ks], bhi[t][ks], acc, 0, 0, 0);
                acc = __builtin_amdgcn_mfma_f32_16x16x32_bf16(Ah[ks], blo[t][ks], acc, 0, 0, 0);
                acc = __builtin_amdgcn_mfma_f32_16x16x32_bf16(Ah[ks], bhi[t][ks], acc, 0, 0, 0);
            }
            const int c = col0 + 16 * t + l15;
            const float bv = bias ? bias[c] : 0.f;
            #pragma unroll
            for (int r = 0; r < 4; r++) {
                float v = acc[r] + bv;
                if (relu_out) v = fmaxf(v, 0.f);
                size_t idx = (size_t)(rt * 16 + lg * 4 + r) * 128 + c;
                bf16 h = (bf16)v;
                ohi[idx] = h;
                olo[idx] = (bf16)(v - (float)h);
            }
        }
    }
}

// ---------------- CSR gather aggregation (bf16 messages) + relu + split epilogue ----------------
// Lane l handles feats {2l, 2l+1}: one 4B bf16x2 load per edge. Edge loop unrolled x4 for MLP.

__global__ __launch_bounds__(256) void gather_agg_split(
    const bf16* __restrict__ hhi, const bf16* __restrict__ hlo,
    const int* __restrict__ csrc, const float* __restrict__ cen,
    const int* __restrict__ off, const float* __restrict__ dinv,
    const float* __restrict__ bias,
    bf16* __restrict__ ohi, bf16* __restrict__ olo, int n)
{
    int lane = threadIdx.x & 63;
    int wid  = (blockIdx.x * 256 + threadIdx.x) >> 6;
    int nw   = (gridDim.x * 256) >> 6;

    const int f = 2 * lane;
    float bb0 = bias[f], bb1 = bias[f + 1];

    for (int node = wid; node < n; node += nw) {
        float sn = dinv[node]; sn *= sn;
        size_t nb = (size_t)node * 128 + f;
        bf16x2 sh = *(const bf16x2*)(hhi + nb);
        bf16x2 sl = *(const bf16x2*)(hlo + nb);
        float a0 = fmaf((float)sh[0] + (float)sl[0], sn, bb0);
        float a1 = fmaf((float)sh[1] + (float)sl[1], sn, bb1);

        int e0 = off[node], e1 = off[node + 1];
        int e = e0;
        for (; e + 4 <= e1; e += 4) {
            int s0 = csrc[e], s1 = csrc[e + 1], s2 = csrc[e + 2], s3 = csrc[e + 3];
            float w0 = cen[e], w1 = cen[e + 1], w2 = cen[e + 2], w3 = cen[e + 3];
            bf16x2 r0 = *(const bf16x2*)(hhi + (size_t)s0 * 128 + f);
            bf16x2 r1 = *(const bf16x2*)(hhi + (size_t)s1 * 128 + f);
            bf16x2 r2 = *(const bf16x2*)(hhi + (size_t)s2 * 128 + f);
            bf16x2 r3 = *(const bf16x2*)(hhi + (size_t)s3 * 128 + f);
            a0 = fmaf((float)r0[0], w0, a0); a1 = fmaf((float)r0[1], w0, a1);
            a0 = fmaf((float)r1[0], w1, a0); a1 = fmaf((float)r1[1], w1, a1);
            a0 = fmaf((float)r2[0], w2, a0); a1 = fmaf((float)r2[1], w2, a1);
            a0 = fmaf((float)r3[0], w3, a0); a1 = fmaf((float)r3[1], w3, a1);
        }
        for (; e < e1; e++) {
            int s = csrc[e];
            float w = cen[e];
            bf16x2 r = *(const bf16x2*)(hhi + (size_t)s * 128 + f);
            a0 = fmaf((float)r[0], w, a0);
            a1 = fmaf((float)r[1], w, a1);
        }

        a0 = fmaxf(a0, 0.f);
        a1 = fmaxf(a1, 0.f);
        bf16x2 oh, ol;
        oh[0] = (bf16)a0; ol[0] = (bf16)(a0 - (float)oh[0]);
        oh[1] = (bf16)a1; ol[1] = (bf16)(a1 - (float)oh[1]);
        *(bf16x2*)(ohi + nb) = oh;
        *(bf16x2*)(olo + nb) = ol;
    }
}

// ---------------- out = log_softmax( (hhi+hlo)[N,128] @ W[128,40] + b ) ----------------

__global__ __launch_bounds__(256) void lin2_lsm(
    const bf16* __restrict__ hhi, const bf16* __restrict__ hlo,
    const float* __restrict__ W, const float* __restrict__ bias,
    float* __restrict__ out, int n)
{
    __shared__ float Wl[128 * 40];
    for (int i = threadIdx.x; i < 128 * 40; i += 256) Wl[i] = W[i];
    __syncthreads();

    int lane = threadIdx.x & 63;
    int wid  = (blockIdx.x * 256 + threadIdx.x) >> 6;
    int nw   = (gridDim.x * 256) >> 6;

    for (int row = wid; row < n; row += nw) {
        const bf16* xh = hhi + (size_t)row * 128;
        const bf16* xl = hlo + (size_t)row * 128;
        float acc = -INFINITY;
        if (lane < 40) {
            acc = bias[lane];
            for (int k = 0; k < 128; k++) {
                float xk = (float)xh[k] + (float)xl[k];
                acc = fmaf(xk, Wl[k * 40 + lane], acc);
            }
        }
        float m = acc;
        #pragma unroll
        for (int off2 = 32; off2 >= 1; off2 >>= 1)
            m = fmaxf(m, __shfl_xor(m, off2, 64));
        float ex = (lane < 40) ? __expf(acc - m) : 0.f;
        float s = ex;
        #pragma unroll
        for (int off2 = 32; off2 >= 1; off2 >>= 1)
            s += __shfl_xor(s, off2, 64);
        float ls = __logf(s);
        if (lane < 40) out[(size_t)row * 40 + lane] = acc - m - ls;
    }
}

// ---------------- launch ----------------

static inline size_t align256(size_t x) { return (x + 255) & ~(size_t)255; }

extern "C" void kernel_launch(void* const* d_in, const int* in_sizes, int n_in,
                              void* d_out, int out_size, void* d_ws, size_t ws_size,
                              hipStream_t stream)
{
    const float* x   = (const float*)d_in[0];
    const int*   ei  = (const int*)d_in[1];
    const float* W1  = (const float*)d_in[2];  const float* b1  = (const float*)d_in[3];
    const float* W2  = (const float*)d_in[4];  const float* b2  = (const float*)d_in[5];
    const float* W3  = (const float*)d_in[6];  const float* b3  = (const float*)d_in[7];
    const float* l1w = (const float*)d_in[8];  const float* l1b = (const float*)d_in[9];
    const float* l2w = (const float*)d_in[10]; const float* l2b = (const float*)d_in[11];

    const int N = in_sizes[0] / 128;
    const int E = in_sizes[1] / 2;
    const int* src = ei;
    const int* dst = ei + E;

    char* wsb = (char*)d_ws;
    size_t o = 0;
    int*   deg  = (int*)(wsb + o);   o = align256(o + (size_t)N * 4);        // reused as cursor
    int*   off  = (int*)(wsb + o);   o = align256(o + (size_t)(N + 1) * 4);
    int*   bsum = (int*)(wsb + o);   o = align256(o + (size_t)4096 * 4);
    int*   csrc = (int*)(wsb + o);   o = align256(o + (size_t)E * 4);
    float* cen  = (float*)(wsb + o); o = align256(o + (size_t)E * 4);
    float* dinv = (float*)(wsb + o); o = align256(o + (size_t)N * 4);
    bf16*  ahi  = (bf16*)(wsb + o);  o = align256(o + (size_t)N * 128 * 2);
    bf16*  alo  = (bf16*)(wsb + o);  o = align256(o + (size_t)N * 128 * 2);
    bf16*  hhi  = (bf16*)(wsb + o);  o = align256(o + (size_t)N * 128 * 2);
    bf16*  hlo  = (bf16*)(wsb + o);  o = align256(o + (size_t)N * 128 * 2);

    float* outp = (float*)d_out;
    const int nb = (N + SCHUNK - 1) / SCHUNK;

    // ---- CSR build (once) ----
    zero_i32<<<(N + 255) / 256, 256, 0, stream>>>(deg, N);
    count_deg<<<2048, 256, 0, stream>>>(dst, deg, E);
    finalize_dinv<<<(N + 255) / 256, 256, 0, stream>>>(deg, dinv, N);
    scan_p1<<<nb, 256, 0, stream>>>(deg, bsum, N);
    scan_p2<<<1, 64, 0, stream>>>(bsum, off, nb, N);
    scan_p3<<<nb, 256, 0, stream>>>(deg, bsum, off, deg /*cursor*/, N);
    fill_csr<<<2048, 256, 0, stream>>>(src, dst, dinv, off, deg, csrc, cen, E);

    // ---- split x ----
    split_relu<<<4096, 256, 0, stream>>>(x, ahi, alo, (long long)N * 32, 0);

    // ---- layer 1 ----
    gemm_mfma<<<2048, 256, 0, stream>>>(ahi, alo, W1, nullptr, hhi, hlo, N, 0);
    gather_agg_split<<<4096, 256, 0, stream>>>(hhi, hlo, csrc, cen, off, dinv, b1, ahi, alo, N);

    // ---- layer 2 ----
    gemm_mfma<<<2048, 256, 0, stream>>>(ahi, alo, W2, nullptr, hhi, hlo, N, 0);
    gather_agg_split<<<4096, 256, 0, stream>>>(hhi, hlo, csrc, cen, off, dinv, b2, ahi, alo, N);

    // ---- layer 3 ----
    gemm_mfma<<<2048, 256, 0, stream>>>(ahi, alo, W3, nullptr, hhi, hlo, N, 0);
    gather_agg_split<<<4096, 256, 0, stream>>>(hhi, hlo, csrc, cen, off, dinv, b3, ahi, alo, N);

    // ---- lin1 (+bias+relu) -> split bf16 ----
    gemm_mfma<<<2048, 256, 0, stream>>>(ahi, alo, l1w, l1b, hhi, hlo, N, 1);

    // ---- lin2 + log_softmax ----
    lin2_lsm<<<2048, 256, 0, stream>>>(hhi, hlo, l2w, l2b, outp, N);
}

// Round 6
// 650.487 us; speedup vs baseline: 14.8163x; 1.0430x over previous
//
#include <hip/hip_runtime.h>
#include <math.h>

typedef __bf16 bf16;
typedef bf16  bf16x8 __attribute__((ext_vector_type(8)));
typedef bf16  bf16x4 __attribute__((ext_vector_type(4)));
typedef bf16  bf16x2 __attribute__((ext_vector_type(2)));
typedef float f32x4  __attribute__((ext_vector_type(4)));

// ---------------- degree / norm precompute ----------------

__global__ void zero_i32(int* __restrict__ p, int n) {
    int i = blockIdx.x * blockDim.x + threadIdx.x;
    if (i < n) p[i] = 0;
}

__global__ void count_deg(const int* __restrict__ dst, int* __restrict__ deg, int E) {
    int i = blockIdx.x * blockDim.x + threadIdx.x;
    int stride = gridDim.x * blockDim.x;
    for (; i < E; i += stride) atomicAdd(&deg[dst[i]], 1);
}

__global__ void finalize_dinv(const int* __restrict__ deg, float* __restrict__ dinv, int n) {
    int i = blockIdx.x * blockDim.x + threadIdx.x;
    if (i < n) dinv[i] = rsqrtf((float)deg[i] + 1.0f);   // +1 self-loop
}

// ---------------- parallel 3-phase exclusive scan ----------------
#define SCHUNK 2048

__global__ __launch_bounds__(256) void scan_p1(const int* __restrict__ deg,
                                               int* __restrict__ bsum, int n) {
    int base = blockIdx.x * SCHUNK;
    int s = 0;
    for (int i = threadIdx.x; i < SCHUNK; i += 256) {
        int idx = base + i;
        s += (idx < n) ? deg[idx] : 0;
    }
    #pragma unroll
    for (int o = 32; o >= 1; o >>= 1) s += __shfl_xor(s, o, 64);
    __shared__ int ws[4];
    if ((threadIdx.x & 63) == 0) ws[threadIdx.x >> 6] = s;
    __syncthreads();
    if (threadIdx.x == 0) bsum[blockIdx.x] = ws[0] + ws[1] + ws[2] + ws[3];
}

// single wave: exclusive-scan bsum[nb] in place; writes off[n] = total
__global__ __launch_bounds__(64) void scan_p2(int* __restrict__ bsum,
                                              int* __restrict__ off, int nb, int n) {
    int lane = threadIdx.x;
    __shared__ int carry_s;
    if (lane == 0) carry_s = 0;
    __syncthreads();
    for (int base = 0; base < nb; base += 64) {
        int i = base + lane;
        int v = (i < nb) ? bsum[i] : 0;
        int x = v;
        #pragma unroll
        for (int o = 1; o < 64; o <<= 1) {
            int t = __shfl_up(x, o, 64);
            if (lane >= o) x += t;
        }
        int carry = carry_s;
        if (i < nb) bsum[i] = carry + x - v;   // exclusive
        int total = __shfl(x, 63, 64);
        __syncthreads();
        if (lane == 0) carry_s = carry + total;
        __syncthreads();
    }
    if (lane == 0) off[n] = carry_s;
}

__global__ __launch_bounds__(256) void scan_p3(const int* __restrict__ deg,
                                               const int* __restrict__ bsum,
                                               int* __restrict__ off,
                                               int* __restrict__ cursor, int n) {
    int base = blockIdx.x * SCHUNK + (int)threadIdx.x * 8;
    int v[8]; int s = 0;
    #pragma unroll
    for (int j = 0; j < 8; j++) {
        int idx = base + j;
        v[j] = (idx < n) ? deg[idx] : 0;
        s += v[j];
    }
    int lane = threadIdx.x & 63, wv = threadIdx.x >> 6;
    int x = s;
    #pragma unroll
    for (int o = 1; o < 64; o <<= 1) {
        int t = __shfl_up(x, o, 64);
        if (lane >= o) x += t;
    }
    __shared__ int wsum[4];
    if (lane == 63) wsum[wv] = x;
    __syncthreads();
    int wbase = 0;
    #pragma unroll
    for (int w = 0; w < 4; w++) if (w < wv) wbase += wsum[w];
    int tbase = bsum[blockIdx.x] + wbase + x - s;   // exclusive prefix for this thread
    #pragma unroll
    for (int j = 0; j < 8; j++) {
        int idx = base + j;
        if (idx < n) { off[idx] = tbase; cursor[idx] = 0; tbase += v[j]; }
    }
}

// bucket-fill CSR: erec[p] = {src, bits(dinv[src]*dinv[dst])} — single 8B scatter per edge
__global__ void fill_csr(const int* __restrict__ src, const int* __restrict__ dst,
                         const float* __restrict__ dinv, const int* __restrict__ off,
                         int* __restrict__ cursor, uint2* __restrict__ erec, int E)
{
    int i = blockIdx.x * blockDim.x + threadIdx.x;
    int stride = gridDim.x * blockDim.x;
    for (; i < E; i += stride) {
        int s = src[i], d = dst[i];
        int p = off[d] + atomicAdd(&cursor[d], 1);
        uint2 r;
        r.x = (unsigned)s;
        r.y = __float_as_uint(dinv[s] * dinv[d]);
        erec[p] = r;
    }
}

// ---------------- fp32 -> split bf16 (hi/lo) ----------------

__global__ __launch_bounds__(256) void split_relu(
    const float* __restrict__ in, bf16* __restrict__ hi, bf16* __restrict__ lo,
    long long n4, int do_relu)
{
    long long i = (long long)blockIdx.x * blockDim.x + threadIdx.x;
    long long stride = (long long)gridDim.x * blockDim.x;
    for (; i < n4; i += stride) {
        float4 v = *(const float4*)(in + i * 4);
        if (do_relu) {
            v.x = fmaxf(v.x, 0.f); v.y = fmaxf(v.y, 0.f);
            v.z = fmaxf(v.z, 0.f); v.w = fmaxf(v.w, 0.f);
        }
        bf16x4 h, l;
        h[0] = (bf16)v.x; l[0] = (bf16)(v.x - (float)h[0]);
        h[1] = (bf16)v.y; l[1] = (bf16)(v.y - (float)h[1]);
        h[2] = (bf16)v.z; l[2] = (bf16)(v.z - (float)h[2]);
        h[3] = (bf16)v.w; l[3] = (bf16)(v.w - (float)h[3]);
        *(bf16x4*)(hi + i * 4) = h;
        *(bf16x4*)(lo + i * 4) = l;
    }
}

// ---------------- MFMA GEMM: (Ahi+Alo)[N,128] @ W[128,128] (+bias,+relu) -> split bf16 ----------------

__global__ __launch_bounds__(256) void gemm_mfma(
    const bf16* __restrict__ ahi, const bf16* __restrict__ alo,
    const float* __restrict__ W, const float* __restrict__ bias,
    bf16* __restrict__ ohi, bf16* __restrict__ olo, int n_rows, int relu_out)
{
    const int lane = threadIdx.x & 63;
    const int wv   = threadIdx.x >> 6;
    const int col0 = wv * 32;
    const int l15  = lane & 15;
    const int lg   = lane >> 4;

    bf16x8 bhi[2][4], blo[2][4];
    #pragma unroll
    for (int t = 0; t < 2; t++) {
        int c = col0 + 16 * t + l15;
        #pragma unroll
        for (int ks = 0; ks < 4; ks++) {
            #pragma unroll
            for (int j = 0; j < 8; j++) {
                float wvv = W[(ks * 32 + lg * 8 + j) * 128 + c];
                bf16 h = (bf16)wvv;
                bhi[t][ks][j] = h;
                blo[t][ks][j] = (bf16)(wvv - (float)h);
            }
        }
    }

    const int nrt = n_rows >> 4;
    for (int rt = blockIdx.x; rt < nrt; rt += gridDim.x) {
        const int row = rt * 16 + l15;
        const bf16* pah = ahi + (size_t)row * 128 + lg * 8;
        const bf16* pal = alo + (size_t)row * 128 + lg * 8;
        bf16x8 Ah[4], Al[4];
        #pragma unroll
        for (int ks = 0; ks < 4; ks++) {
            Ah[ks] = *(const bf16x8*)(pah + ks * 32);
            Al[ks] = *(const bf16x8*)(pal + ks * 32);
        }
        #pragma unroll
        for (int t = 0; t < 2; t++) {
            f32x4 acc = {0.f, 0.f, 0.f, 0.f};
            #pragma unroll
            for (int ks = 0; ks < 4; ks++) {
                acc = __builtin_amdgcn_mfma_f32_16x16x32_bf16(Al[ks], bhi[t][ks], acc, 0, 0, 0);
                acc = __builtin_amdgcn_mfma_f32_16x16x32_bf16(Ah[ks], blo[t][ks], acc, 0, 0, 0);
                acc = __builtin_amdgcn_mfma_f32_16x16x32_bf16(Ah[ks], bhi[t][ks], acc, 0, 0, 0);
            }
            const int c = col0 + 16 * t + l15;
            const float bv = bias ? bias[c] : 0.f;
            #pragma unroll
            for (int r = 0; r < 4; r++) {
                float v = acc[r] + bv;
                if (relu_out) v = fmaxf(v, 0.f);
                size_t idx = (size_t)(rt * 16 + lg * 4 + r) * 128 + c;
                bf16 h = (bf16)v;
                ohi[idx] = h;
                olo[idx] = (bf16)(v - (float)h);
            }
        }
    }
}

// ---------------- CSR gather aggregation (bf16 messages) + relu + split epilogue ----------------
// Lane l handles feats {2l, 2l+1}: one 4B bf16x2 load per edge. Edge loop unrolled x4 for MLP.
// Edge record is packed 8B {src, weight}.

__global__ __launch_bounds__(256) void gather_agg_split(
    const bf16* __restrict__ hhi, const bf16* __restrict__ hlo,
    const uint2* __restrict__ erec, const int* __restrict__ off,
    const float* __restrict__ dinv, const float* __restrict__ bias,
    bf16* __restrict__ ohi, bf16* __restrict__ olo, int n)
{
    int lane = threadIdx.x & 63;
    int wid  = (blockIdx.x * 256 + threadIdx.x) >> 6;
    int nw   = (gridDim.x * 256) >> 6;

    const int f = 2 * lane;
    float bb0 = bias[f], bb1 = bias[f + 1];

    for (int node = wid; node < n; node += nw) {
        float sn = dinv[node]; sn *= sn;
        size_t nb = (size_t)node * 128 + f;
        bf16x2 sh = *(const bf16x2*)(hhi + nb);
        bf16x2 sl = *(const bf16x2*)(hlo + nb);
        float a0 = fmaf((float)sh[0] + (float)sl[0], sn, bb0);
        float a1 = fmaf((float)sh[1] + (float)sl[1], sn, bb1);

        int e0 = off[node], e1 = off[node + 1];
        int e = e0;
        for (; e + 4 <= e1; e += 4) {
            uint2 q0 = erec[e], q1 = erec[e + 1], q2 = erec[e + 2], q3 = erec[e + 3];
            float w0 = __uint_as_float(q0.y), w1 = __uint_as_float(q1.y);
            float w2 = __uint_as_float(q2.y), w3 = __uint_as_float(q3.y);
            bf16x2 r0 = *(const bf16x2*)(hhi + (size_t)q0.x * 128 + f);
            bf16x2 r1 = *(const bf16x2*)(hhi + (size_t)q1.x * 128 + f);
            bf16x2 r2 = *(const bf16x2*)(hhi + (size_t)q2.x * 128 + f);
            bf16x2 r3 = *(const bf16x2*)(hhi + (size_t)q3.x * 128 + f);
            a0 = fmaf((float)r0[0], w0, a0); a1 = fmaf((float)r0[1], w0, a1);
            a0 = fmaf((float)r1[0], w1, a0); a1 = fmaf((float)r1[1], w1, a1);
            a0 = fmaf((float)r2[0], w2, a0); a1 = fmaf((float)r2[1], w2, a1);
            a0 = fmaf((float)r3[0], w3, a0); a1 = fmaf((float)r3[1], w3, a1);
        }
        for (; e < e1; e++) {
            uint2 q = erec[e];
            float w = __uint_as_float(q.y);
            bf16x2 r = *(const bf16x2*)(hhi + (size_t)q.x * 128 + f);
            a0 = fmaf((float)r[0], w, a0);
            a1 = fmaf((float)r[1], w, a1);
        }

        a0 = fmaxf(a0, 0.f);
        a1 = fmaxf(a1, 0.f);
        bf16x2 oh, ol;
        oh[0] = (bf16)a0; ol[0] = (bf16)(a0 - (float)oh[0]);
        oh[1] = (bf16)a1; ol[1] = (bf16)(a1 - (float)oh[1]);
        *(bf16x2*)(ohi + nb) = oh;
        *(bf16x2*)(olo + nb) = ol;
    }
}

// ---------------- out = log_softmax( (hhi+hlo)[N,128] @ W[128,40] + b ) ----------------

__global__ __launch_bounds__(256) void lin2_lsm(
    const bf16* __restrict__ hhi, const bf16* __restrict__ hlo,
    const float* __restrict__ W, const float* __restrict__ bias,
    float* __restrict__ out, int n)
{
    __shared__ float Wl[128 * 40];
    for (int i = threadIdx.x; i < 128 * 40; i += 256) Wl[i] = W[i];
    __syncthreads();

    int lane = threadIdx.x & 63;
    int wid  = (blockIdx.x * 256 + threadIdx.x) >> 6;
    int nw   = (gridDim.x * 256) >> 6;

    for (int row = wid; row < n; row += nw) {
        const bf16* xh = hhi + (size_t)row * 128;
        const bf16* xl = hlo + (size_t)row * 128;
        float acc = -INFINITY;
        if (lane < 40) {
            acc = bias[lane];
            for (int k = 0; k < 128; k++) {
                float xk = (float)xh[k] + (float)xl[k];
                acc = fmaf(xk, Wl[k * 40 + lane], acc);
            }
        }
        float m = acc;
        #pragma unroll
        for (int off2 = 32; off2 >= 1; off2 >>= 1)
            m = fmaxf(m, __shfl_xor(m, off2, 64));
        float ex = (lane < 40) ? __expf(acc - m) : 0.f;
        float s = ex;
        #pragma unroll
        for (int off2 = 32; off2 >= 1; off2 >>= 1)
            s += __shfl_xor(s, off2, 64);
        float ls = __logf(s);
        if (lane < 40) out[(size_t)row * 40 + lane] = acc - m - ls;
    }
}

// ---------------- launch ----------------

static inline size_t align256(size_t x) { return (x + 255) & ~(size_t)255; }

extern "C" void kernel_launch(void* const* d_in, const int* in_sizes, int n_in,
                              void* d_out, int out_size, void* d_ws, size_t ws_size,
                              hipStream_t stream)
{
    const float* x   = (const float*)d_in[0];
    const int*   ei  = (const int*)d_in[1];
    const float* W1  = (const float*)d_in[2];  const float* b1  = (const float*)d_in[3];
    const float* W2  = (const float*)d_in[4];  const float* b2  = (const float*)d_in[5];
    const float* W3  = (const float*)d_in[6];  const float* b3  = (const float*)d_in[7];
    const float* l1w = (const float*)d_in[8];  const float* l1b = (const float*)d_in[9];
    const float* l2w = (const float*)d_in[10]; const float* l2b = (const float*)d_in[11];

    const int N = in_sizes[0] / 128;
    const int E = in_sizes[1] / 2;
    const int* src = ei;
    const int* dst = ei + E;

    char* wsb = (char*)d_ws;
    size_t o = 0;
    int*   deg  = (int*)(wsb + o);   o = align256(o + (size_t)N * 4);        // reused as cursor
    int*   off  = (int*)(wsb + o);   o = align256(o + (size_t)(N + 1) * 4);
    int*   bsum = (int*)(wsb + o);   o = align256(o + (size_t)4096 * 4);
    uint2* erec = (uint2*)(wsb + o); o = align256(o + (size_t)E * 8);
    float* dinv = (float*)(wsb + o); o = align256(o + (size_t)N * 4);
    bf16*  ahi  = (bf16*)(wsb + o);  o = align256(o + (size_t)N * 128 * 2);
    bf16*  alo  = (bf16*)(wsb + o);  o = align256(o + (size_t)N * 128 * 2);
    bf16*  hhi  = (bf16*)(wsb + o);  o = align256(o + (size_t)N * 128 * 2);
    bf16*  hlo  = (bf16*)(wsb + o);  o = align256(o + (size_t)N * 128 * 2);

    float* outp = (float*)d_out;
    const int nb = (N + SCHUNK - 1) / SCHUNK;

    // ---- CSR build (once) ----
    zero_i32<<<(N + 255) / 256, 256, 0, stream>>>(deg, N);
    count_deg<<<2048, 256, 0, stream>>>(dst, deg, E);
    finalize_dinv<<<(N + 255) / 256, 256, 0, stream>>>(deg, dinv, N);
    scan_p1<<<nb, 256, 0, stream>>>(deg, bsum, N);
    scan_p2<<<1, 64, 0, stream>>>(bsum, off, nb, N);
    scan_p3<<<nb, 256, 0, stream>>>(deg, bsum, off, deg /*cursor*/, N);
    fill_csr<<<2048, 256, 0, stream>>>(src, dst, dinv, off, deg, erec, E);

    // ---- split x ----
    split_relu<<<4096, 256, 0, stream>>>(x, ahi, alo, (long long)N * 32, 0);

    // ---- layer 1 ----
    gemm_mfma<<<2048, 256, 0, stream>>>(ahi, alo, W1, nullptr, hhi, hlo, N, 0);
    gather_agg_split<<<4096, 256, 0, stream>>>(hhi, hlo, erec, off, dinv, b1, ahi, alo, N);

    // ---- layer 2 ----
    gemm_mfma<<<2048, 256, 0, stream>>>(ahi, alo, W2, nullptr, hhi, hlo, N, 0);
    gather_agg_split<<<4096, 256, 0, stream>>>(hhi, hlo, erec, off, dinv, b2, ahi, alo, N);

    // ---- layer 3 ----
    gemm_mfma<<<2048, 256, 0, stream>>>(ahi, alo, W3, nullptr, hhi, hlo, N, 0);
    gather_agg_split<<<4096, 256, 0, stream>>>(hhi, hlo, erec, off, dinv, b3, ahi, alo, N);

    // ---- lin1 (+bias+relu) -> split bf16 ----
    gemm_mfma<<<2048, 256, 0, stream>>>(ahi, alo, l1w, l1b, hhi, hlo, N, 1);

    // ---- lin2 + log_softmax ----
    lin2_lsm<<<2048, 256, 0, stream>>>(hhi, hlo, l2w, l2b, outp, N);
}

// Round 7
// 579.702 us; speedup vs baseline: 16.6254x; 1.1221x over previous
//
#include <hip/hip_runtime.h>
#include <math.h>

typedef __bf16 bf16;
typedef bf16  bf16x8 __attribute__((ext_vector_type(8)));
typedef bf16  bf16x4 __attribute__((ext_vector_type(4)));
typedef bf16  bf16x2 __attribute__((ext_vector_type(2)));
typedef float f32x4  __attribute__((ext_vector_type(4)));

// ---------------- degree / norm precompute ----------------

__global__ void zero_i32(int* __restrict__ p, int n) {
    int i = blockIdx.x * blockDim.x + threadIdx.x;
    if (i < n) p[i] = 0;
}

__global__ void count_deg(const int* __restrict__ dst, int* __restrict__ deg, int E) {
    int i = blockIdx.x * blockDim.x + threadIdx.x;
    int stride = gridDim.x * blockDim.x;
    for (; i < E; i += stride) atomicAdd(&deg[dst[i]], 1);
}

__global__ void finalize_dinv(const int* __restrict__ deg, float* __restrict__ dinv, int n) {
    int i = blockIdx.x * blockDim.x + threadIdx.x;
    if (i < n) dinv[i] = rsqrtf((float)deg[i] + 1.0f);   // +1 self-loop
}

// ---------------- parallel 3-phase exclusive scan ----------------
#define SCHUNK 2048

__global__ __launch_bounds__(256) void scan_p1(const int* __restrict__ deg,
                                               int* __restrict__ bsum, int n) {
    int base = blockIdx.x * SCHUNK;
    int s = 0;
    for (int i = threadIdx.x; i < SCHUNK; i += 256) {
        int idx = base + i;
        s += (idx < n) ? deg[idx] : 0;
    }
    #pragma unroll
    for (int o = 32; o >= 1; o >>= 1) s += __shfl_xor(s, o, 64);
    __shared__ int ws[4];
    if ((threadIdx.x & 63) == 0) ws[threadIdx.x >> 6] = s;
    __syncthreads();
    if (threadIdx.x == 0) bsum[blockIdx.x] = ws[0] + ws[1] + ws[2] + ws[3];
}

// single wave: exclusive-scan bsum[nb] in place; writes off[n] = total
__global__ __launch_bounds__(64) void scan_p2(int* __restrict__ bsum,
                                              int* __restrict__ off, int nb, int n) {
    int lane = threadIdx.x;
    __shared__ int carry_s;
    if (lane == 0) carry_s = 0;
    __syncthreads();
    for (int base = 0; base < nb; base += 64) {
        int i = base + lane;
        int v = (i < nb) ? bsum[i] : 0;
        int x = v;
        #pragma unroll
        for (int o = 1; o < 64; o <<= 1) {
            int t = __shfl_up(x, o, 64);
            if (lane >= o) x += t;
        }
        int carry = carry_s;
        if (i < nb) bsum[i] = carry + x - v;   // exclusive
        int total = __shfl(x, 63, 64);
        __syncthreads();
        if (lane == 0) carry_s = carry + total;
        __syncthreads();
    }
    if (lane == 0) off[n] = carry_s;
}

__global__ __launch_bounds__(256) void scan_p3(const int* __restrict__ deg,
                                               const int* __restrict__ bsum,
                                               int* __restrict__ off,
                                               int* __restrict__ cursor, int n) {
    int base = blockIdx.x * SCHUNK + (int)threadIdx.x * 8;
    int v[8]; int s = 0;
    #pragma unroll
    for (int j = 0; j < 8; j++) {
        int idx = base + j;
        v[j] = (idx < n) ? deg[idx] : 0;
        s += v[j];
    }
    int lane = threadIdx.x & 63, wv = threadIdx.x >> 6;
    int x = s;
    #pragma unroll
    for (int o = 1; o < 64; o <<= 1) {
        int t = __shfl_up(x, o, 64);
        if (lane >= o) x += t;
    }
    __shared__ int wsum[4];
    if (lane == 63) wsum[wv] = x;
    __syncthreads();
    int wbase = 0;
    #pragma unroll
    for (int w = 0; w < 4; w++) if (w < wv) wbase += wsum[w];
    int tbase = bsum[blockIdx.x] + wbase + x - s;   // exclusive prefix for this thread
    #pragma unroll
    for (int j = 0; j < 8; j++) {
        int idx = base + j;
        if (idx < n) { off[idx] = tbase; cursor[idx] = 0; tbase += v[j]; }
    }
}

// bucket-fill CSR: erec[p] = {src, bits(dinv[src]*dinv[dst])} — single 8B scatter per edge
__global__ void fill_csr(const int* __restrict__ src, const int* __restrict__ dst,
                         const float* __restrict__ dinv, const int* __restrict__ off,
                         int* __restrict__ cursor, uint2* __restrict__ erec, int E)
{
    int i = blockIdx.x * blockDim.x + threadIdx.x;
    int stride = gridDim.x * blockDim.x;
    for (; i < E; i += stride) {
        int s = src[i], d = dst[i];
        int p = off[d] + atomicAdd(&cursor[d], 1);
        uint2 r;
        r.x = (unsigned)s;
        r.y = __float_as_uint(dinv[s] * dinv[d]);
        erec[p] = r;
    }
}

// ---------------- fp32 -> split bf16 (hi/lo) ----------------

__global__ __launch_bounds__(256) void split_relu(
    const float* __restrict__ in, bf16* __restrict__ hi, bf16* __restrict__ lo,
    long long n4, int do_relu)
{
    long long i = (long long)blockIdx.x * blockDim.x + threadIdx.x;
    long long stride = (long long)gridDim.x * blockDim.x;
    for (; i < n4; i += stride) {
        float4 v = *(const float4*)(in + i * 4);
        if (do_relu) {
            v.x = fmaxf(v.x, 0.f); v.y = fmaxf(v.y, 0.f);
            v.z = fmaxf(v.z, 0.f); v.w = fmaxf(v.w, 0.f);
        }
        bf16x4 h, l;
        h[0] = (bf16)v.x; l[0] = (bf16)(v.x - (float)h[0]);
        h[1] = (bf16)v.y; l[1] = (bf16)(v.y - (float)h[1]);
        h[2] = (bf16)v.z; l[2] = (bf16)(v.z - (float)h[2]);
        h[3] = (bf16)v.w; l[3] = (bf16)(v.w - (float)h[3]);
        *(bf16x4*)(hi + i * 4) = h;
        *(bf16x4*)(lo + i * 4) = l;
    }
}

// ---------------- MFMA GEMM: (Ahi+Alo)[N,128] @ W[128,128] (+bias,+relu) -> split bf16 ----------------

__global__ __launch_bounds__(256) void gemm_mfma(
    const bf16* __restrict__ ahi, const bf16* __restrict__ alo,
    const float* __restrict__ W, const float* __restrict__ bias,
    bf16* __restrict__ ohi, bf16* __restrict__ olo, int n_rows, int relu_out)
{
    const int lane = threadIdx.x & 63;
    const int wv   = threadIdx.x >> 6;
    const int col0 = wv * 32;
    const int l15  = lane & 15;
    const int lg   = lane >> 4;

    bf16x8 bhi[2][4], blo[2][4];
    #pragma unroll
    for (int t = 0; t < 2; t++) {
        int c = col0 + 16 * t + l15;
        #pragma unroll
        for (int ks = 0; ks < 4; ks++) {
            #pragma unroll
            for (int j = 0; j < 8; j++) {
                float wvv = W[(ks * 32 + lg * 8 + j) * 128 + c];
                bf16 h = (bf16)wvv;
                bhi[t][ks][j] = h;
                blo[t][ks][j] = (bf16)(wvv - (float)h);
            }
        }
    }

    const int nrt = n_rows >> 4;
    for (int rt = blockIdx.x; rt < nrt; rt += gridDim.x) {
        const int row = rt * 16 + l15;
        const bf16* pah = ahi + (size_t)row * 128 + lg * 8;
        const bf16* pal = alo + (size_t)row * 128 + lg * 8;
        bf16x8 Ah[4], Al[4];
        #pragma unroll
        for (int ks = 0; ks < 4; ks++) {
            Ah[ks] = *(const bf16x8*)(pah + ks * 32);
            Al[ks] = *(const bf16x8*)(pal + ks * 32);
        }
        #pragma unroll
        for (int t = 0; t < 2; t++) {
            f32x4 acc = {0.f, 0.f, 0.f, 0.f};
            #pragma unroll
            for (int ks = 0; ks < 4; ks++) {
                acc = __builtin_amdgcn_mfma_f32_16x16x32_bf16(Al[ks], bhi[t][ks], acc, 0, 0, 0);
                acc = __builtin_amdgcn_mfma_f32_16x16x32_bf16(Ah[ks], blo[t][ks], acc, 0, 0, 0);
                acc = __builtin_amdgcn_mfma_f32_16x16x32_bf16(Ah[ks], bhi[t][ks], acc, 0, 0, 0);
            }
            const int c = col0 + 16 * t + l15;
            const float bv = bias ? bias[c] : 0.f;
            #pragma unroll
            for (int r = 0; r < 4; r++) {
                float v = acc[r] + bv;
                if (relu_out) v = fmaxf(v, 0.f);
                size_t idx = (size_t)(rt * 16 + lg * 4 + r) * 128 + c;
                bf16 h = (bf16)v;
                ohi[idx] = h;
                olo[idx] = (bf16)(v - (float)h);
            }
        }
    }
}

// ---------------- CSR gather aggregation (bf16 messages) + relu + split epilogue ----------------

__global__ __launch_bounds__(256) void gather_agg_split(
    const bf16* __restrict__ hhi, const bf16* __restrict__ hlo,
    const uint2* __restrict__ erec, const int* __restrict__ off,
    const float* __restrict__ dinv, const float* __restrict__ bias,
    bf16* __restrict__ ohi, bf16* __restrict__ olo, int n)
{
    int lane = threadIdx.x & 63;
    int wid  = (blockIdx.x * 256 + threadIdx.x) >> 6;
    int nw   = (gridDim.x * 256) >> 6;

    const int f = 2 * lane;
    float bb0 = bias[f], bb1 = bias[f + 1];

    for (int node = wid; node < n; node += nw) {
        float sn = dinv[node]; sn *= sn;
        size_t nb = (size_t)node * 128 + f;
        bf16x2 sh = *(const bf16x2*)(hhi + nb);
        bf16x2 sl = *(const bf16x2*)(hlo + nb);
        float a0 = fmaf((float)sh[0] + (float)sl[0], sn, bb0);
        float a1 = fmaf((float)sh[1] + (float)sl[1], sn, bb1);

        int e0 = off[node], e1 = off[node + 1];
        int e = e0;
        for (; e + 4 <= e1; e += 4) {
            uint2 q0 = erec[e], q1 = erec[e + 1], q2 = erec[e + 2], q3 = erec[e + 3];
            float w0 = __uint_as_float(q0.y), w1 = __uint_as_float(q1.y);
            float w2 = __uint_as_float(q2.y), w3 = __uint_as_float(q3.y);
            bf16x2 r0 = *(const bf16x2*)(hhi + (size_t)q0.x * 128 + f);
            bf16x2 r1 = *(const bf16x2*)(hhi + (size_t)q1.x * 128 + f);
            bf16x2 r2 = *(const bf16x2*)(hhi + (size_t)q2.x * 128 + f);
            bf16x2 r3 = *(const bf16x2*)(hhi + (size_t)q3.x * 128 + f);
            a0 = fmaf((float)r0[0], w0, a0); a1 = fmaf((float)r0[1], w0, a1);
            a0 = fmaf((float)r1[0], w1, a0); a1 = fmaf((float)r1[1], w1, a1);
            a0 = fmaf((float)r2[0], w2, a0); a1 = fmaf((float)r2[1], w2, a1);
            a0 = fmaf((float)r3[0], w3, a0); a1 = fmaf((float)r3[1], w3, a1);
        }
        for (; e < e1; e++) {
            uint2 q = erec[e];
            float w = __uint_as_float(q.y);
            bf16x2 r = *(const bf16x2*)(hhi + (size_t)q.x * 128 + f);
            a0 = fmaf((float)r[0], w, a0);
            a1 = fmaf((float)r[1], w, a1);
        }

        a0 = fmaxf(a0, 0.f);
        a1 = fmaxf(a1, 0.f);
        bf16x2 oh, ol;
        oh[0] = (bf16)a0; ol[0] = (bf16)(a0 - (float)oh[0]);
        oh[1] = (bf16)a1; ol[1] = (bf16)(a1 - (float)oh[1]);
        *(bf16x2*)(ohi + nb) = oh;
        *(bf16x2*)(olo + nb) = ol;
    }
}

// ---------------- lin2 + log_softmax via MFMA ----------------
// Logits [N,40] padded to 48 cols = 3 MFMA col-tiles. One wave per 16-row tile.
// C layout: col = t*16 + (lane&15), row = rt*16 + (lane>>4)*4 + r.
// Row-reduce (max, sumexp) across the 16-lane l15 group via shfl_xor {1,2,4,8}.

__global__ __launch_bounds__(256) void lin2_mfma_lsm(
    const bf16* __restrict__ hhi, const bf16* __restrict__ hlo,
    const float* __restrict__ W, const float* __restrict__ bias,
    float* __restrict__ out, int n)
{
    const int lane = threadIdx.x & 63;
    const int l15  = lane & 15;
    const int lg   = lane >> 4;

    // B fragments for 3 col tiles (cols >= 40 zeroed)
    bf16x8 bhi[3][4], blo[3][4];
    float bb[3];
    #pragma unroll
    for (int t = 0; t < 3; t++) {
        int c = t * 16 + l15;
        bool valid = c < 40;
        bb[t] = valid ? bias[c] : 0.f;
        #pragma unroll
        for (int ks = 0; ks < 4; ks++) {
            #pragma unroll
            for (int j = 0; j < 8; j++) {
                float wv = valid ? W[(ks * 32 + lg * 8 + j) * 40 + c] : 0.f;
                bf16 h = (bf16)wv;
                bhi[t][ks][j] = h;
                blo[t][ks][j] = (bf16)(wv - (float)h);
            }
        }
    }

    const bool v2 = (l15 < 8);   // tile-2 col validity (cols 32..39)

    int wtile = (blockIdx.x * 256 + threadIdx.x) >> 6;
    int nwt   = (gridDim.x * 256) >> 6;
    int ntiles = (n + 15) >> 4;

    for (int rt = wtile; rt < ntiles; rt += nwt) {
        int arow = rt * 16 + l15;
        if (arow >= n) arow = n - 1;
        const bf16* pah = hhi + (size_t)arow * 128 + lg * 8;
        const bf16* pal = hlo + (size_t)arow * 128 + lg * 8;
        bf16x8 Ah[4], Al[4];
        #pragma unroll
        for (int ks = 0; ks < 4; ks++) {
            Ah[ks] = *(const bf16x8*)(pah + ks * 32);
            Al[ks] = *(const bf16x8*)(pal + ks * 32);
        }
        f32x4 acc[3];
        #pragma unroll
        for (int t = 0; t < 3; t++) {
            acc[t] = (f32x4){0.f, 0.f, 0.f, 0.f};
            #pragma unroll
            for (int ks = 0; ks < 4; ks++) {
                acc[t] = __builtin_amdgcn_mfma_f32_16x16x32_bf16(Al[ks], bhi[t][ks], acc[t], 0, 0, 0);
                acc[t] = __builtin_amdgcn_mfma_f32_16x16x32_bf16(Ah[ks], blo[t][ks], acc[t], 0, 0, 0);
                acc[t] = __builtin_amdgcn_mfma_f32_16x16x32_bf16(Ah[ks], bhi[t][ks], acc[t], 0, 0, 0);
            }
        }
        #pragma unroll
        for (int r = 0; r < 4; r++) {
            float l0 = acc[0][r] + bb[0];
            float l1 = acc[1][r] + bb[1];
            float l2 = acc[2][r] + bb[2];
            float m = fmaxf(l0, l1);
            m = fmaxf(m, v2 ? l2 : -INFINITY);
            #pragma unroll
            for (int o = 8; o >= 1; o >>= 1)
                m = fmaxf(m, __shfl_xor(m, o, 64));
            float s = __expf(l0 - m) + __expf(l1 - m) + (v2 ? __expf(l2 - m) : 0.f);
            #pragma unroll
            for (int o = 8; o >= 1; o >>= 1)
                s += __shfl_xor(s, o, 64);
            float ls = __logf(s);
            int orow = rt * 16 + lg * 4 + r;
            if (orow < n) {
                float* op = out + (size_t)orow * 40;
                op[l15]      = l0 - m - ls;
                op[16 + l15] = l1 - m - ls;
                if (v2) op[32 + l15] = l2 - m - ls;
            }
        }
    }
}

// ---------------- launch ----------------

static inline size_t align256(size_t x) { return (x + 255) & ~(size_t)255; }

extern "C" void kernel_launch(void* const* d_in, const int* in_sizes, int n_in,
                              void* d_out, int out_size, void* d_ws, size_t ws_size,
                              hipStream_t stream)
{
    const float* x   = (const float*)d_in[0];
    const int*   ei  = (const int*)d_in[1];
    const float* W1  = (const float*)d_in[2];  const float* b1  = (const float*)d_in[3];
    const float* W2  = (const float*)d_in[4];  const float* b2  = (const float*)d_in[5];
    const float* W3  = (const float*)d_in[6];  const float* b3  = (const float*)d_in[7];
    const float* l1w = (const float*)d_in[8];  const float* l1b = (const float*)d_in[9];
    const float* l2w = (const float*)d_in[10]; const float* l2b = (const float*)d_in[11];

    const int N = in_sizes[0] / 128;
    const int E = in_sizes[1] / 2;
    const int* src = ei;
    const int* dst = ei + E;

    char* wsb = (char*)d_ws;
    size_t o = 0;
    int*   deg  = (int*)(wsb + o);   o = align256(o + (size_t)N * 4);        // reused as cursor
    int*   off  = (int*)(wsb + o);   o = align256(o + (size_t)(N + 1) * 4);
    int*   bsum = (int*)(wsb + o);   o = align256(o + (size_t)4096 * 4);
    uint2* erec = (uint2*)(wsb + o); o = align256(o + (size_t)E * 8);
    float* dinv = (float*)(wsb + o); o = align256(o + (size_t)N * 4);
    bf16*  ahi  = (bf16*)(wsb + o);  o = align256(o + (size_t)N * 128 * 2);
    bf16*  alo  = (bf16*)(wsb + o);  o = align256(o + (size_t)N * 128 * 2);
    bf16*  hhi  = (bf16*)(wsb + o);  o = align256(o + (size_t)N * 128 * 2);
    bf16*  hlo  = (bf16*)(wsb + o);  o = align256(o + (size_t)N * 128 * 2);

    float* outp = (float*)d_out;
    const int nb = (N + SCHUNK - 1) / SCHUNK;

    // ---- CSR build (once) ----
    zero_i32<<<(N + 255) / 256, 256, 0, stream>>>(deg, N);
    count_deg<<<2048, 256, 0, stream>>>(dst, deg, E);
    finalize_dinv<<<(N + 255) / 256, 256, 0, stream>>>(deg, dinv, N);
    scan_p1<<<nb, 256, 0, stream>>>(deg, bsum, N);
    scan_p2<<<1, 64, 0, stream>>>(bsum, off, nb, N);
    scan_p3<<<nb, 256, 0, stream>>>(deg, bsum, off, deg /*cursor*/, N);
    fill_csr<<<2048, 256, 0, stream>>>(src, dst, dinv, off, deg, erec, E);

    // ---- split x ----
    split_relu<<<4096, 256, 0, stream>>>(x, ahi, alo, (long long)N * 32, 0);

    // ---- layer 1 ----
    gemm_mfma<<<2048, 256, 0, stream>>>(ahi, alo, W1, nullptr, hhi, hlo, N, 0);
    gather_agg_split<<<4096, 256, 0, stream>>>(hhi, hlo, erec, off, dinv, b1, ahi, alo, N);

    // ---- layer 2 ----
    gemm_mfma<<<2048, 256, 0, stream>>>(ahi, alo, W2, nullptr, hhi, hlo, N, 0);
    gather_agg_split<<<4096, 256, 0, stream>>>(hhi, hlo, erec, off, dinv, b2, ahi, alo, N);

    // ---- layer 3 ----
    gemm_mfma<<<2048, 256, 0, stream>>>(ahi, alo, W3, nullptr, hhi, hlo, N, 0);
    gather_agg_split<<<4096, 256, 0, stream>>>(hhi, hlo, erec, off, dinv, b3, ahi, alo, N);

    // ---- lin1 (+bias+relu) -> split bf16 ----
    gemm_mfma<<<2048, 256, 0, stream>>>(ahi, alo, l1w, l1b, hhi, hlo, N, 1);

    // ---- lin2 + log_softmax (MFMA) ----
    lin2_mfma_lsm<<<2048, 256, 0, stream>>>(hhi, hlo, l2w, l2b, outp, N);
}

// Round 8
// 576.733 us; speedup vs baseline: 16.7110x; 1.0051x over previous
//
#include <hip/hip_runtime.h>
#include <math.h>

typedef __bf16 bf16;
typedef bf16  bf16x8 __attribute__((ext_vector_type(8)));
typedef bf16  bf16x4 __attribute__((ext_vector_type(4)));
typedef bf16  bf16x2 __attribute__((ext_vector_type(2)));
typedef float f32x4  __attribute__((ext_vector_type(4)));

// ---------------- degree / norm precompute ----------------

__global__ void zero_i32(int* __restrict__ p, int n) {
    int i = blockIdx.x * blockDim.x + threadIdx.x;
    if (i < n) p[i] = 0;
}

__global__ void count_deg(const int* __restrict__ dst, int* __restrict__ deg, int E) {
    int i = blockIdx.x * blockDim.x + threadIdx.x;
    int stride = gridDim.x * blockDim.x;
    for (; i < E; i += stride) atomicAdd(&deg[dst[i]], 1);
}

__global__ void finalize_dinv(const int* __restrict__ deg, float* __restrict__ dinv, int n) {
    int i = blockIdx.x * blockDim.x + threadIdx.x;
    if (i < n) dinv[i] = rsqrtf((float)deg[i] + 1.0f);   // +1 self-loop
}

// ---------------- parallel 3-phase exclusive scan ----------------
#define SCHUNK 2048

__global__ __launch_bounds__(256) void scan_p1(const int* __restrict__ deg,
                                               int* __restrict__ bsum, int n) {
    int base = blockIdx.x * SCHUNK;
    int s = 0;
    for (int i = threadIdx.x; i < SCHUNK; i += 256) {
        int idx = base + i;
        s += (idx < n) ? deg[idx] : 0;
    }
    #pragma unroll
    for (int o = 32; o >= 1; o >>= 1) s += __shfl_xor(s, o, 64);
    __shared__ int ws[4];
    if ((threadIdx.x & 63) == 0) ws[threadIdx.x >> 6] = s;
    __syncthreads();
    if (threadIdx.x == 0) bsum[blockIdx.x] = ws[0] + ws[1] + ws[2] + ws[3];
}

// single wave: exclusive-scan bsum[nb] in place; writes off[n] = total
__global__ __launch_bounds__(64) void scan_p2(int* __restrict__ bsum,
                                              int* __restrict__ off, int nb, int n) {
    int lane = threadIdx.x;
    __shared__ int carry_s;
    if (lane == 0) carry_s = 0;
    __syncthreads();
    for (int base = 0; base < nb; base += 64) {
        int i = base + lane;
        int v = (i < nb) ? bsum[i] : 0;
        int x = v;
        #pragma unroll
        for (int o = 1; o < 64; o <<= 1) {
            int t = __shfl_up(x, o, 64);
            if (lane >= o) x += t;
        }
        int carry = carry_s;
        if (i < nb) bsum[i] = carry + x - v;   // exclusive
        int total = __shfl(x, 63, 64);
        __syncthreads();
        if (lane == 0) carry_s = carry + total;
        __syncthreads();
    }
    if (lane == 0) off[n] = carry_s;
}

__global__ __launch_bounds__(256) void scan_p3(const int* __restrict__ deg,
                                               const int* __restrict__ bsum,
                                               int* __restrict__ off,
                                               int* __restrict__ cursor, int n) {
    int base = blockIdx.x * SCHUNK + (int)threadIdx.x * 8;
    int v[8]; int s = 0;
    #pragma unroll
    for (int j = 0; j < 8; j++) {
        int idx = base + j;
        v[j] = (idx < n) ? deg[idx] : 0;
        s += v[j];
    }
    int lane = threadIdx.x & 63, wv = threadIdx.x >> 6;
    int x = s;
    #pragma unroll
    for (int o = 1; o < 64; o <<= 1) {
        int t = __shfl_up(x, o, 64);
        if (lane >= o) x += t;
    }
    __shared__ int wsum[4];
    if (lane == 63) wsum[wv] = x;
    __syncthreads();
    int wbase = 0;
    #pragma unroll
    for (int w = 0; w < 4; w++) if (w < wv) wbase += wsum[w];
    int tbase = bsum[blockIdx.x] + wbase + x - s;   // exclusive prefix for this thread
    #pragma unroll
    for (int j = 0; j < 8; j++) {
        int idx = base + j;
        if (idx < n) { off[idx] = tbase; cursor[idx] = 0; tbase += v[j]; }
    }
}

// bucket-fill CSR, XCD-class-filtered: block class (blockIdx&7) handles edges with
// (dst>>8)&7 == class, so all writers of a dst-bucket's CSR lines live on one XCD
// (blockIdx%8 -> XCD heuristic) and the 8B records merge in that XCD's L2 before
// one eviction, instead of one full-line writeback per record.
__global__ __launch_bounds__(256) void fill_csr(
    const int* __restrict__ src, const int* __restrict__ dst,
    const float* __restrict__ dinv, const int* __restrict__ off,
    int* __restrict__ cursor, uint2* __restrict__ erec, int E)
{
    const int xcls = blockIdx.x & 7;
    int i = (blockIdx.x >> 3) * 256 + threadIdx.x;
    const int stride = (gridDim.x >> 3) * 256;
    for (; i < E; i += stride) {
        int d = dst[i];
        if (((d >> 8) & 7) != xcls) continue;
        int s = src[i];
        int p = off[d] + atomicAdd(&cursor[d], 1);
        uint2 r;
        r.x = (unsigned)s;
        r.y = __float_as_uint(dinv[s] * dinv[d]);
        erec[p] = r;
    }
}

// ---------------- fp32 -> split bf16 (hi/lo) ----------------

__global__ __launch_bounds__(256) void split_relu(
    const float* __restrict__ in, bf16* __restrict__ hi, bf16* __restrict__ lo,
    long long n4, int do_relu)
{
    long long i = (long long)blockIdx.x * blockDim.x + threadIdx.x;
    long long stride = (long long)gridDim.x * blockDim.x;
    for (; i < n4; i += stride) {
        float4 v = *(const float4*)(in + i * 4);
        if (do_relu) {
            v.x = fmaxf(v.x, 0.f); v.y = fmaxf(v.y, 0.f);
            v.z = fmaxf(v.z, 0.f); v.w = fmaxf(v.w, 0.f);
        }
        bf16x4 h, l;
        h[0] = (bf16)v.x; l[0] = (bf16)(v.x - (float)h[0]);
        h[1] = (bf16)v.y; l[1] = (bf16)(v.y - (float)h[1]);
        h[2] = (bf16)v.z; l[2] = (bf16)(v.z - (float)h[2]);
        h[3] = (bf16)v.w; l[3] = (bf16)(v.w - (float)h[3]);
        *(bf16x4*)(hi + i * 4) = h;
        *(bf16x4*)(lo + i * 4) = l;
    }
}

// ---------------- MFMA GEMM: (Ahi+Alo)[N,128] @ W[128,128] (+bias,+relu) -> split bf16 ----------------

__global__ __launch_bounds__(256) void gemm_mfma(
    const bf16* __restrict__ ahi, const bf16* __restrict__ alo,
    const float* __restrict__ W, const float* __restrict__ bias,
    bf16* __restrict__ ohi, bf16* __restrict__ olo, int n_rows, int relu_out)
{
    const int lane = threadIdx.x & 63;
    const int wv   = threadIdx.x >> 6;
    const int col0 = wv * 32;
    const int l15  = lane & 15;
    const int lg   = lane >> 4;

    bf16x8 bhi[2][4], blo[2][4];
    #pragma unroll
    for (int t = 0; t < 2; t++) {
        int c = col0 + 16 * t + l15;
        #pragma unroll
        for (int ks = 0; ks < 4; ks++) {
            #pragma unroll
            for (int j = 0; j < 8; j++) {
                float wvv = W[(ks * 32 + lg * 8 + j) * 128 + c];
                bf16 h = (bf16)wvv;
                bhi[t][ks][j] = h;
                blo[t][ks][j] = (bf16)(wvv - (float)h);
            }
        }
    }

    const int nrt = n_rows >> 4;
    for (int rt = blockIdx.x; rt < nrt; rt += gridDim.x) {
        const int row = rt * 16 + l15;
        const bf16* pah = ahi + (size_t)row * 128 + lg * 8;
        const bf16* pal = alo + (size_t)row * 128 + lg * 8;
        bf16x8 Ah[4], Al[4];
        #pragma unroll
        for (int ks = 0; ks < 4; ks++) {
            Ah[ks] = *(const bf16x8*)(pah + ks * 32);
            Al[ks] = *(const bf16x8*)(pal + ks * 32);
        }
        #pragma unroll
        for (int t = 0; t < 2; t++) {
            f32x4 acc = {0.f, 0.f, 0.f, 0.f};
            #pragma unroll
            for (int ks = 0; ks < 4; ks++) {
                acc = __builtin_amdgcn_mfma_f32_16x16x32_bf16(Al[ks], bhi[t][ks], acc, 0, 0, 0);
                acc = __builtin_amdgcn_mfma_f32_16x16x32_bf16(Ah[ks], blo[t][ks], acc, 0, 0, 0);
                acc = __builtin_amdgcn_mfma_f32_16x16x32_bf16(Ah[ks], bhi[t][ks], acc, 0, 0, 0);
            }
            const int c = col0 + 16 * t + l15;
            const float bv = bias ? bias[c] : 0.f;
            #pragma unroll
            for (int r = 0; r < 4; r++) {
                float v = acc[r] + bv;
                if (relu_out) v = fmaxf(v, 0.f);
                size_t idx = (size_t)(rt * 16 + lg * 4 + r) * 128 + c;
                bf16 h = (bf16)v;
                ohi[idx] = h;
                olo[idx] = (bf16)(v - (float)h);
            }
        }
    }
}

// ---------------- CSR gather aggregation (bf16 messages) + relu + split epilogue ----------------

__global__ __launch_bounds__(256) void gather_agg_split(
    const bf16* __restrict__ hhi, const bf16* __restrict__ hlo,
    const uint2* __restrict__ erec, const int* __restrict__ off,
    const float* __restrict__ dinv, const float* __restrict__ bias,
    bf16* __restrict__ ohi, bf16* __restrict__ olo, int n)
{
    int lane = threadIdx.x & 63;
    int wid  = (blockIdx.x * 256 + threadIdx.x) >> 6;
    int nw   = (gridDim.x * 256) >> 6;

    const int f = 2 * lane;
    float bb0 = bias[f], bb1 = bias[f + 1];

    for (int node = wid; node < n; node += nw) {
        float sn = dinv[node]; sn *= sn;
        size_t nb = (size_t)node * 128 + f;
        bf16x2 sh = *(const bf16x2*)(hhi + nb);
        bf16x2 sl = *(const bf16x2*)(hlo + nb);
        float a0 = fmaf((float)sh[0] + (float)sl[0], sn, bb0);
        float a1 = fmaf((float)sh[1] + (float)sl[1], sn, bb1);

        int e0 = off[node], e1 = off[node + 1];
        int e = e0;
        for (; e + 4 <= e1; e += 4) {
            uint2 q0 = erec[e], q1 = erec[e + 1], q2 = erec[e + 2], q3 = erec[e + 3];
            float w0 = __uint_as_float(q0.y), w1 = __uint_as_float(q1.y);
            float w2 = __uint_as_float(q2.y), w3 = __uint_as_float(q3.y);
            bf16x2 r0 = *(const bf16x2*)(hhi + (size_t)q0.x * 128 + f);
            bf16x2 r1 = *(const bf16x2*)(hhi + (size_t)q1.x * 128 + f);
            bf16x2 r2 = *(const bf16x2*)(hhi + (size_t)q2.x * 128 + f);
            bf16x2 r3 = *(const bf16x2*)(hhi + (size_t)q3.x * 128 + f);
            a0 = fmaf((float)r0[0], w0, a0); a1 = fmaf((float)r0[1], w0, a1);
            a0 = fmaf((float)r1[0], w1, a0); a1 = fmaf((float)r1[1], w1, a1);
            a0 = fmaf((float)r2[0], w2, a0); a1 = fmaf((float)r2[1], w2, a1);
            a0 = fmaf((float)r3[0], w3, a0); a1 = fmaf((float)r3[1], w3, a1);
        }
        for (; e < e1; e++) {
            uint2 q = erec[e];
            float w = __uint_as_float(q.y);
            bf16x2 r = *(const bf16x2*)(hhi + (size_t)q.x * 128 + f);
            a0 = fmaf((float)r[0], w, a0);
            a1 = fmaf((float)r[1], w, a1);
        }

        a0 = fmaxf(a0, 0.f);
        a1 = fmaxf(a1, 0.f);
        bf16x2 oh, ol;
        oh[0] = (bf16)a0; ol[0] = (bf16)(a0 - (float)oh[0]);
        oh[1] = (bf16)a1; ol[1] = (bf16)(a1 - (float)oh[1]);
        *(bf16x2*)(ohi + nb) = oh;
        *(bf16x2*)(olo + nb) = ol;
    }
}

// ---------------- lin2 + log_softmax via MFMA ----------------

__global__ __launch_bounds__(256) void lin2_mfma_lsm(
    const bf16* __restrict__ hhi, const bf16* __restrict__ hlo,
    const float* __restrict__ W, const float* __restrict__ bias,
    float* __restrict__ out, int n)
{
    const int lane = threadIdx.x & 63;
    const int l15  = lane & 15;
    const int lg   = lane >> 4;

    // B fragments for 3 col tiles (cols >= 40 zeroed)
    bf16x8 bhi[3][4], blo[3][4];
    float bb[3];
    #pragma unroll
    for (int t = 0; t < 3; t++) {
        int c = t * 16 + l15;
        bool valid = c < 40;
        bb[t] = valid ? bias[c] : 0.f;
        #pragma unroll
        for (int ks = 0; ks < 4; ks++) {
            #pragma unroll
            for (int j = 0; j < 8; j++) {
                float wv = valid ? W[(ks * 32 + lg * 8 + j) * 40 + c] : 0.f;
                bf16 h = (bf16)wv;
                bhi[t][ks][j] = h;
                blo[t][ks][j] = (bf16)(wv - (float)h);
            }
        }
    }

    const bool v2 = (l15 < 8);   // tile-2 col validity (cols 32..39)

    int wtile = (blockIdx.x * 256 + threadIdx.x) >> 6;
    int nwt   = (gridDim.x * 256) >> 6;
    int ntiles = (n + 15) >> 4;

    for (int rt = wtile; rt < ntiles; rt += nwt) {
        int arow = rt * 16 + l15;
        if (arow >= n) arow = n - 1;
        const bf16* pah = hhi + (size_t)arow * 128 + lg * 8;
        const bf16* pal = hlo + (size_t)arow * 128 + lg * 8;
        bf16x8 Ah[4], Al[4];
        #pragma unroll
        for (int ks = 0; ks < 4; ks++) {
            Ah[ks] = *(const bf16x8*)(pah + ks * 32);
            Al[ks] = *(const bf16x8*)(pal + ks * 32);
        }
        f32x4 acc[3];
        #pragma unroll
        for (int t = 0; t < 3; t++) {
            acc[t] = (f32x4){0.f, 0.f, 0.f, 0.f};
            #pragma unroll
            for (int ks = 0; ks < 4; ks++) {
                acc[t] = __builtin_amdgcn_mfma_f32_16x16x32_bf16(Al[ks], bhi[t][ks], acc[t], 0, 0, 0);
                acc[t] = __builtin_amdgcn_mfma_f32_16x16x32_bf16(Ah[ks], blo[t][ks], acc[t], 0, 0, 0);
                acc[t] = __builtin_amdgcn_mfma_f32_16x16x32_bf16(Ah[ks], bhi[t][ks], acc[t], 0, 0, 0);
            }
        }
        #pragma unroll
        for (int r = 0; r < 4; r++) {
            float l0 = acc[0][r] + bb[0];
            float l1 = acc[1][r] + bb[1];
            float l2 = acc[2][r] + bb[2];
            float m = fmaxf(l0, l1);
            m = fmaxf(m, v2 ? l2 : -INFINITY);
            #pragma unroll
            for (int o = 8; o >= 1; o >>= 1)
                m = fmaxf(m, __shfl_xor(m, o, 64));
            float s = __expf(l0 - m) + __expf(l1 - m) + (v2 ? __expf(l2 - m) : 0.f);
            #pragma unroll
            for (int o = 8; o >= 1; o >>= 1)
                s += __shfl_xor(s, o, 64);
            float ls = __logf(s);
            int orow = rt * 16 + lg * 4 + r;
            if (orow < n) {
                float* op = out + (size_t)orow * 40;
                op[l15]      = l0 - m - ls;
                op[16 + l15] = l1 - m - ls;
                if (v2) op[32 + l15] = l2 - m - ls;
            }
        }
    }
}

// ---------------- launch ----------------

static inline size_t align256(size_t x) { return (x + 255) & ~(size_t)255; }

extern "C" void kernel_launch(void* const* d_in, const int* in_sizes, int n_in,
                              void* d_out, int out_size, void* d_ws, size_t ws_size,
                              hipStream_t stream)
{
    const float* x   = (const float*)d_in[0];
    const int*   ei  = (const int*)d_in[1];
    const float* W1  = (const float*)d_in[2];  const float* b1  = (const float*)d_in[3];
    const float* W2  = (const float*)d_in[4];  const float* b2  = (const float*)d_in[5];
    const float* W3  = (const float*)d_in[6];  const float* b3  = (const float*)d_in[7];
    const float* l1w = (const float*)d_in[8];  const float* l1b = (const float*)d_in[9];
    const float* l2w = (const float*)d_in[10]; const float* l2b = (const float*)d_in[11];

    const int N = in_sizes[0] / 128;
    const int E = in_sizes[1] / 2;
    const int* src = ei;
    const int* dst = ei + E;

    char* wsb = (char*)d_ws;
    size_t o = 0;
    int*   deg  = (int*)(wsb + o);   o = align256(o + (size_t)N * 4);        // reused as cursor
    int*   off  = (int*)(wsb + o);   o = align256(o + (size_t)(N + 1) * 4);
    int*   bsum = (int*)(wsb + o);   o = align256(o + (size_t)4096 * 4);
    uint2* erec = (uint2*)(wsb + o); o = align256(o + (size_t)E * 8);
    float* dinv = (float*)(wsb + o); o = align256(o + (size_t)N * 4);
    bf16*  ahi  = (bf16*)(wsb + o);  o = align256(o + (size_t)N * 128 * 2);
    bf16*  alo  = (bf16*)(wsb + o);  o = align256(o + (size_t)N * 128 * 2);
    bf16*  hhi  = (bf16*)(wsb + o);  o = align256(o + (size_t)N * 128 * 2);
    bf16*  hlo  = (bf16*)(wsb + o);  o = align256(o + (size_t)N * 128 * 2);

    float* outp = (float*)d_out;
    const int nb = (N + SCHUNK - 1) / SCHUNK;

    // ---- CSR build (once) ----
    zero_i32<<<(N + 255) / 256, 256, 0, stream>>>(deg, N);
    count_deg<<<2048, 256, 0, stream>>>(dst, deg, E);
    finalize_dinv<<<(N + 255) / 256, 256, 0, stream>>>(deg, dinv, N);
    scan_p1<<<nb, 256, 0, stream>>>(deg, bsum, N);
    scan_p2<<<1, 64, 0, stream>>>(bsum, off, nb, N);
    scan_p3<<<nb, 256, 0, stream>>>(deg, bsum, off, deg /*cursor*/, N);
    fill_csr<<<2048, 256, 0, stream>>>(src, dst, dinv, off, deg, erec, E);

    // ---- split x ----
    split_relu<<<4096, 256, 0, stream>>>(x, ahi, alo, (long long)N * 32, 0);

    // ---- layer 1 ----
    gemm_mfma<<<2048, 256, 0, stream>>>(ahi, alo, W1, nullptr, hhi, hlo, N, 0);
    gather_agg_split<<<4096, 256, 0, stream>>>(hhi, hlo, erec, off, dinv, b1, ahi, alo, N);

    // ---- layer 2 ----
    gemm_mfma<<<2048, 256, 0, stream>>>(ahi, alo, W2, nullptr, hhi, hlo, N, 0);
    gather_agg_split<<<4096, 256, 0, stream>>>(hhi, hlo, erec, off, dinv, b2, ahi, alo, N);

    // ---- layer 3 ----
    gemm_mfma<<<2048, 256, 0, stream>>>(ahi, alo, W3, nullptr, hhi, hlo, N, 0);
    gather_agg_split<<<4096, 256, 0, stream>>>(hhi, hlo, erec, off, dinv, b3, ahi, alo, N);

    // ---- lin1 (+bias+relu) -> split bf16 ----
    gemm_mfma<<<2048, 256, 0, stream>>>(ahi, alo, l1w, l1b, hhi, hlo, N, 1);

    // ---- lin2 + log_softmax (MFMA) ----
    lin2_mfma_lsm<<<2048, 256, 0, stream>>>(hhi, hlo, l2w, l2b, outp, N);
}

// Round 9
// 569.208 us; speedup vs baseline: 16.9319x; 1.0132x over previous
//
#include <hip/hip_runtime.h>
#include <math.h>

typedef __bf16 bf16;
typedef bf16  bf16x8 __attribute__((ext_vector_type(8)));
typedef bf16  bf16x4 __attribute__((ext_vector_type(4)));
typedef bf16  bf16x2 __attribute__((ext_vector_type(2)));
typedef float f32x4  __attribute__((ext_vector_type(4)));

// ---------------- degree / norm precompute ----------------

__global__ void zero_i32(int* __restrict__ p, int n) {
    int i = blockIdx.x * blockDim.x + threadIdx.x;
    if (i < n) p[i] = 0;
}

__global__ void count_deg(const int* __restrict__ dst, int* __restrict__ deg, int E) {
    int i = blockIdx.x * blockDim.x + threadIdx.x;
    int stride = gridDim.x * blockDim.x;
    for (; i < E; i += stride) atomicAdd(&deg[dst[i]], 1);
}

__global__ void finalize_dinv(const int* __restrict__ deg, float* __restrict__ dinv, int n) {
    int i = blockIdx.x * blockDim.x + threadIdx.x;
    if (i < n) dinv[i] = rsqrtf((float)deg[i] + 1.0f);   // +1 self-loop
}

// ---------------- parallel 3-phase exclusive scan ----------------
#define SCHUNK 2048

__global__ __launch_bounds__(256) void scan_p1(const int* __restrict__ deg,
                                               int* __restrict__ bsum, int n) {
    int base = blockIdx.x * SCHUNK;
    int s = 0;
    for (int i = threadIdx.x; i < SCHUNK; i += 256) {
        int idx = base + i;
        s += (idx < n) ? deg[idx] : 0;
    }
    #pragma unroll
    for (int o = 32; o >= 1; o >>= 1) s += __shfl_xor(s, o, 64);
    __shared__ int ws[4];
    if ((threadIdx.x & 63) == 0) ws[threadIdx.x >> 6] = s;
    __syncthreads();
    if (threadIdx.x == 0) bsum[blockIdx.x] = ws[0] + ws[1] + ws[2] + ws[3];
}

__global__ __launch_bounds__(64) void scan_p2(int* __restrict__ bsum,
                                              int* __restrict__ off, int nb, int n) {
    int lane = threadIdx.x;
    __shared__ int carry_s;
    if (lane == 0) carry_s = 0;
    __syncthreads();
    for (int base = 0; base < nb; base += 64) {
        int i = base + lane;
        int v = (i < nb) ? bsum[i] : 0;
        int x = v;
        #pragma unroll
        for (int o = 1; o < 64; o <<= 1) {
            int t = __shfl_up(x, o, 64);
            if (lane >= o) x += t;
        }
        int carry = carry_s;
        if (i < nb) bsum[i] = carry + x - v;   // exclusive
        int total = __shfl(x, 63, 64);
        __syncthreads();
        if (lane == 0) carry_s = carry + total;
        __syncthreads();
    }
    if (lane == 0) off[n] = carry_s;
}

__global__ __launch_bounds__(256) void scan_p3(const int* __restrict__ deg,
                                               const int* __restrict__ bsum,
                                               int* __restrict__ off,
                                               int* __restrict__ cursor, int n) {
    int base = blockIdx.x * SCHUNK + (int)threadIdx.x * 8;
    int v[8]; int s = 0;
    #pragma unroll
    for (int j = 0; j < 8; j++) {
        int idx = base + j;
        v[j] = (idx < n) ? deg[idx] : 0;
        s += v[j];
    }
    int lane = threadIdx.x & 63, wv = threadIdx.x >> 6;
    int x = s;
    #pragma unroll
    for (int o = 1; o < 64; o <<= 1) {
        int t = __shfl_up(x, o, 64);
        if (lane >= o) x += t;
    }
    __shared__ int wsum[4];
    if (lane == 63) wsum[wv] = x;
    __syncthreads();
    int wbase = 0;
    #pragma unroll
    for (int w = 0; w < 4; w++) if (w < wv) wbase += wsum[w];
    int tbase = bsum[blockIdx.x] + wbase + x - s;   // exclusive prefix for this thread
    #pragma unroll
    for (int j = 0; j < 8; j++) {
        int idx = base + j;
        if (idx < n) { off[idx] = tbase; cursor[idx] = 0; tbase += v[j]; }
    }
}

// bucket-fill CSR: erec[p] = {src, bits(dinv[src]*dinv[dst])} — single 8B scatter per edge
__global__ void fill_csr(const int* __restrict__ src, const int* __restrict__ dst,
                         const float* __restrict__ dinv, const int* __restrict__ off,
                         int* __restrict__ cursor, uint2* __restrict__ erec, int E)
{
    int i = blockIdx.x * blockDim.x + threadIdx.x;
    int stride = gridDim.x * blockDim.x;
    for (; i < E; i += stride) {
        int s = src[i], d = dst[i];
        int p = off[d] + atomicAdd(&cursor[d], 1);
        uint2 r;
        r.x = (unsigned)s;
        r.y = __float_as_uint(dinv[s] * dinv[d]);
        erec[p] = r;
    }
}

// ---------------- fp32 -> split bf16 (hi/lo) ----------------

__global__ __launch_bounds__(256) void split_relu(
    const float* __restrict__ in, bf16* __restrict__ hi, bf16* __restrict__ lo,
    long long n4, int do_relu)
{
    long long i = (long long)blockIdx.x * blockDim.x + threadIdx.x;
    long long stride = (long long)gridDim.x * blockDim.x;
    for (; i < n4; i += stride) {
        float4 v = *(const float4*)(in + i * 4);
        if (do_relu) {
            v.x = fmaxf(v.x, 0.f); v.y = fmaxf(v.y, 0.f);
            v.z = fmaxf(v.z, 0.f); v.w = fmaxf(v.w, 0.f);
        }
        bf16x4 h, l;
        h[0] = (bf16)v.x; l[0] = (bf16)(v.x - (float)h[0]);
        h[1] = (bf16)v.y; l[1] = (bf16)(v.y - (float)h[1]);
        h[2] = (bf16)v.z; l[2] = (bf16)(v.z - (float)h[2]);
        h[3] = (bf16)v.w; l[3] = (bf16)(v.w - (float)h[3]);
        *(bf16x4*)(hi + i * 4) = h;
        *(bf16x4*)(lo + i * 4) = l;
    }
}

// ---------------- MFMA GEMM (swapped operands): C^T = W^T @ A^T ----------------
// A-operand = W fragments (built once per wave), B-operand = node features.
// D layout: col(l15) = node-in-tile, row(lg*4+r) = out-channel-in-tile
// -> lane owns 4 CONSECUTIVE out-channels of one node: packed bf16x4 8B stores.

__global__ __launch_bounds__(256) void gemm_mfma(
    const bf16* __restrict__ ahi, const bf16* __restrict__ alo,
    const float* __restrict__ W, const float* __restrict__ bias,
    bf16* __restrict__ ohi, bf16* __restrict__ olo, int n_rows, int relu_out)
{
    const int lane = threadIdx.x & 63;
    const int wv   = threadIdx.x >> 6;
    const int col0 = wv * 32;
    const int l15  = lane & 15;
    const int lg   = lane >> 4;

    // W^T fragments (A-operand): lane row = out-channel (col0+16t+l15), k = ks*32+lg*8+j
    bf16x8 whi[2][4], wlo[2][4];
    #pragma unroll
    for (int t = 0; t < 2; t++) {
        int c = col0 + 16 * t + l15;
        #pragma unroll
        for (int ks = 0; ks < 4; ks++) {
            #pragma unroll
            for (int j = 0; j < 8; j++) {
                float wvv = W[(ks * 32 + lg * 8 + j) * 128 + c];
                bf16 h = (bf16)wvv;
                whi[t][ks][j] = h;
                wlo[t][ks][j] = (bf16)(wvv - (float)h);
            }
        }
    }

    const int nrt = n_rows >> 4;
    for (int rt = blockIdx.x; rt < nrt; rt += gridDim.x) {
        const int row = rt * 16 + l15;     // node (B-operand col)
        const bf16* pah = ahi + (size_t)row * 128 + lg * 8;
        const bf16* pal = alo + (size_t)row * 128 + lg * 8;
        bf16x8 Ah[4], Al[4];
        #pragma unroll
        for (int ks = 0; ks < 4; ks++) {
            Ah[ks] = *(const bf16x8*)(pah + ks * 32);
            Al[ks] = *(const bf16x8*)(pal + ks * 32);
        }
        #pragma unroll
        for (int t = 0; t < 2; t++) {
            f32x4 acc = {0.f, 0.f, 0.f, 0.f};
            #pragma unroll
            for (int ks = 0; ks < 4; ks++) {
                acc = __builtin_amdgcn_mfma_f32_16x16x32_bf16(whi[t][ks], Al[ks], acc, 0, 0, 0);
                acc = __builtin_amdgcn_mfma_f32_16x16x32_bf16(wlo[t][ks], Ah[ks], acc, 0, 0, 0);
                acc = __builtin_amdgcn_mfma_f32_16x16x32_bf16(whi[t][ks], Ah[ks], acc, 0, 0, 0);
            }
            const int c0 = col0 + 16 * t + lg * 4;   // first of 4 consecutive out-channels
            f32x4 bv = {0.f, 0.f, 0.f, 0.f};
            if (bias) bv = *(const f32x4*)(bias + c0);
            bf16x4 h, l;
            #pragma unroll
            for (int r = 0; r < 4; r++) {
                float v = acc[r] + bv[r];
                if (relu_out) v = fmaxf(v, 0.f);
                h[r] = (bf16)v;
                l[r] = (bf16)(v - (float)h[r]);
            }
            size_t base = (size_t)(rt * 16 + l15) * 128 + c0;
            *(bf16x4*)(ohi + base) = h;
            *(bf16x4*)(olo + base) = l;
        }
    }
}

// ---------------- CSR gather aggregation (bf16 messages) + relu + split epilogue ----------------

__global__ __launch_bounds__(256) void gather_agg_split(
    const bf16* __restrict__ hhi, const bf16* __restrict__ hlo,
    const uint2* __restrict__ erec, const int* __restrict__ off,
    const float* __restrict__ dinv, const float* __restrict__ bias,
    bf16* __restrict__ ohi, bf16* __restrict__ olo, int n)
{
    int lane = threadIdx.x & 63;
    int wid  = (blockIdx.x * 256 + threadIdx.x) >> 6;
    int nw   = (gridDim.x * 256) >> 6;

    const int f = 2 * lane;
    float bb0 = bias[f], bb1 = bias[f + 1];

    for (int node = wid; node < n; node += nw) {
        float sn = dinv[node]; sn *= sn;
        size_t nb = (size_t)node * 128 + f;
        bf16x2 sh = *(const bf16x2*)(hhi + nb);
        bf16x2 sl = *(const bf16x2*)(hlo + nb);
        float a0 = fmaf((float)sh[0] + (float)sl[0], sn, bb0);
        float a1 = fmaf((float)sh[1] + (float)sl[1], sn, bb1);

        int e0 = off[node], e1 = off[node + 1];
        int e = e0;
        for (; e + 4 <= e1; e += 4) {
            uint2 q0 = erec[e], q1 = erec[e + 1], q2 = erec[e + 2], q3 = erec[e + 3];
            float w0 = __uint_as_float(q0.y), w1 = __uint_as_float(q1.y);
            float w2 = __uint_as_float(q2.y), w3 = __uint_as_float(q3.y);
            bf16x2 r0 = *(const bf16x2*)(hhi + (size_t)q0.x * 128 + f);
            bf16x2 r1 = *(const bf16x2*)(hhi + (size_t)q1.x * 128 + f);
            bf16x2 r2 = *(const bf16x2*)(hhi + (size_t)q2.x * 128 + f);
            bf16x2 r3 = *(const bf16x2*)(hhi + (size_t)q3.x * 128 + f);
            a0 = fmaf((float)r0[0], w0, a0); a1 = fmaf((float)r0[1], w0, a1);
            a0 = fmaf((float)r1[0], w1, a0); a1 = fmaf((float)r1[1], w1, a1);
            a0 = fmaf((float)r2[0], w2, a0); a1 = fmaf((float)r2[1], w2, a1);
            a0 = fmaf((float)r3[0], w3, a0); a1 = fmaf((float)r3[1], w3, a1);
        }
        for (; e < e1; e++) {
            uint2 q = erec[e];
            float w = __uint_as_float(q.y);
            bf16x2 r = *(const bf16x2*)(hhi + (size_t)q.x * 128 + f);
            a0 = fmaf((float)r[0], w, a0);
            a1 = fmaf((float)r[1], w, a1);
        }

        a0 = fmaxf(a0, 0.f);
        a1 = fmaxf(a1, 0.f);
        bf16x2 oh, ol;
        oh[0] = (bf16)a0; ol[0] = (bf16)(a0 - (float)oh[0]);
        oh[1] = (bf16)a1; ol[1] = (bf16)(a1 - (float)oh[1]);
        *(bf16x2*)(ohi + nb) = oh;
        *(bf16x2*)(olo + nb) = ol;
    }
}

// ---------------- lin2 + log_softmax via MFMA (swapped operands) ----------------
// D: col(l15)=node, row(lg*4+r)=out-class. Lane owns 4 consecutive classes of one node.
// Per-node reduce across lg groups: shfl_xor {16, 32}. float4 output stores.

__global__ __launch_bounds__(256) void lin2_mfma_lsm(
    const bf16* __restrict__ hhi, const bf16* __restrict__ hlo,
    const float* __restrict__ W, const float* __restrict__ bias,
    float* __restrict__ out, int n)
{
    const int lane = threadIdx.x & 63;
    const int l15  = lane & 15;
    const int lg   = lane >> 4;

    // W^T fragments for 3 col tiles (classes >= 40 zeroed)
    bf16x8 whi[3][4], wlo[3][4];
    #pragma unroll
    for (int t = 0; t < 3; t++) {
        int c = t * 16 + l15;
        bool valid = c < 40;
        #pragma unroll
        for (int ks = 0; ks < 4; ks++) {
            #pragma unroll
            for (int j = 0; j < 8; j++) {
                float wv = valid ? W[(ks * 32 + lg * 8 + j) * 40 + c] : 0.f;
                bf16 h = (bf16)wv;
                whi[t][ks][j] = h;
                wlo[t][ks][j] = (bf16)(wv - (float)h);
            }
        }
    }
    // per-lane 4 consecutive class indices per tile: c0(t) = t*16 + lg*4
    f32x4 bb[3];
    bool vstore[3];
    #pragma unroll
    for (int t = 0; t < 3; t++) {
        int c0 = t * 16 + lg * 4;
        vstore[t] = (c0 < 40);
        if (vstore[t]) bb[t] = *(const f32x4*)(bias + c0);
        else bb[t] = (f32x4){0.f, 0.f, 0.f, 0.f};
    }

    int wtile = (blockIdx.x * 256 + threadIdx.x) >> 6;
    int nwt   = (gridDim.x * 256) >> 6;
    int ntiles = (n + 15) >> 4;

    for (int rt = wtile; rt < ntiles; rt += nwt) {
        int arow = rt * 16 + l15;
        if (arow >= n) arow = n - 1;
        const bf16* pah = hhi + (size_t)arow * 128 + lg * 8;
        const bf16* pal = hlo + (size_t)arow * 128 + lg * 8;
        bf16x8 Ah[4], Al[4];
        #pragma unroll
        for (int ks = 0; ks < 4; ks++) {
            Ah[ks] = *(const bf16x8*)(pah + ks * 32);
            Al[ks] = *(const bf16x8*)(pal + ks * 32);
        }
        f32x4 acc[3];
        #pragma unroll
        for (int t = 0; t < 3; t++) {
            acc[t] = (f32x4){0.f, 0.f, 0.f, 0.f};
            #pragma unroll
            for (int ks = 0; ks < 4; ks++) {
                acc[t] = __builtin_amdgcn_mfma_f32_16x16x32_bf16(whi[t][ks], Al[ks], acc[t], 0, 0, 0);
                acc[t] = __builtin_amdgcn_mfma_f32_16x16x32_bf16(wlo[t][ks], Ah[ks], acc[t], 0, 0, 0);
                acc[t] = __builtin_amdgcn_mfma_f32_16x16x32_bf16(whi[t][ks], Ah[ks], acc[t], 0, 0, 0);
            }
        }
        // logits for this lane: acc[t][r] + bb[t][r] (valid iff vstore[t])
        float m = -INFINITY;
        #pragma unroll
        for (int t = 0; t < 3; t++) {
            if (vstore[t]) {
                #pragma unroll
                for (int r = 0; r < 4; r++) m = fmaxf(m, acc[t][r] + bb[t][r]);
            }
        }
        m = fmaxf(m, __shfl_xor(m, 16, 64));
        m = fmaxf(m, __shfl_xor(m, 32, 64));
        float s = 0.f;
        #pragma unroll
        for (int t = 0; t < 3; t++) {
            if (vstore[t]) {
                #pragma unroll
                for (int r = 0; r < 4; r++) s += __expf(acc[t][r] + bb[t][r] - m);
            }
        }
        s += __shfl_xor(s, 16, 64);
        s += __shfl_xor(s, 32, 64);
        float ls = __logf(s) + m;

        int node = rt * 16 + l15;
        if (node < n) {
            #pragma unroll
            for (int t = 0; t < 3; t++) {
                if (vstore[t]) {
                    f32x4 o;
                    #pragma unroll
                    for (int r = 0; r < 4; r++) o[r] = acc[t][r] + bb[t][r] - ls;
                    *(f32x4*)(out + (size_t)node * 40 + t * 16 + lg * 4) = o;
                }
            }
        }
    }
}

// ---------------- launch ----------------

static inline size_t align256(size_t x) { return (x + 255) & ~(size_t)255; }

extern "C" void kernel_launch(void* const* d_in, const int* in_sizes, int n_in,
                              void* d_out, int out_size, void* d_ws, size_t ws_size,
                              hipStream_t stream)
{
    const float* x   = (const float*)d_in[0];
    const int*   ei  = (const int*)d_in[1];
    const float* W1  = (const float*)d_in[2];  const float* b1  = (const float*)d_in[3];
    const float* W2  = (const float*)d_in[4];  const float* b2  = (const float*)d_in[5];
    const float* W3  = (const float*)d_in[6];  const float* b3  = (const float*)d_in[7];
    const float* l1w = (const float*)d_in[8];  const float* l1b = (const float*)d_in[9];
    const float* l2w = (const float*)d_in[10]; const float* l2b = (const float*)d_in[11];

    const int N = in_sizes[0] / 128;
    const int E = in_sizes[1] / 2;
    const int* src = ei;
    const int* dst = ei + E;

    char* wsb = (char*)d_ws;
    size_t o = 0;
    int*   deg  = (int*)(wsb + o);   o = align256(o + (size_t)N * 4);        // reused as cursor
    int*   off  = (int*)(wsb + o);   o = align256(o + (size_t)(N + 1) * 4);
    int*   bsum = (int*)(wsb + o);   o = align256(o + (size_t)4096 * 4);
    uint2* erec = (uint2*)(wsb + o); o = align256(o + (size_t)E * 8);
    float* dinv = (float*)(wsb + o); o = align256(o + (size_t)N * 4);
    bf16*  ahi  = (bf16*)(wsb + o);  o = align256(o + (size_t)N * 128 * 2);
    bf16*  alo  = (bf16*)(wsb + o);  o = align256(o + (size_t)N * 128 * 2);
    bf16*  hhi  = (bf16*)(wsb + o);  o = align256(o + (size_t)N * 128 * 2);
    bf16*  hlo  = (bf16*)(wsb + o);  o = align256(o + (size_t)N * 128 * 2);

    float* outp = (float*)d_out;
    const int nb = (N + SCHUNK - 1) / SCHUNK;

    // ---- CSR build (once) ----
    zero_i32<<<(N + 255) / 256, 256, 0, stream>>>(deg, N);
    count_deg<<<2048, 256, 0, stream>>>(dst, deg, E);
    finalize_dinv<<<(N + 255) / 256, 256, 0, stream>>>(deg, dinv, N);
    scan_p1<<<nb, 256, 0, stream>>>(deg, bsum, N);
    scan_p2<<<1, 64, 0, stream>>>(bsum, off, nb, N);
    scan_p3<<<nb, 256, 0, stream>>>(deg, bsum, off, deg /*cursor*/, N);
    fill_csr<<<2048, 256, 0, stream>>>(src, dst, dinv, off, deg, erec, E);

    // ---- split x ----
    split_relu<<<4096, 256, 0, stream>>>(x, ahi, alo, (long long)N * 32, 0);

    // ---- layer 1 ----
    gemm_mfma<<<1024, 256, 0, stream>>>(ahi, alo, W1, nullptr, hhi, hlo, N, 0);
    gather_agg_split<<<4096, 256, 0, stream>>>(hhi, hlo, erec, off, dinv, b1, ahi, alo, N);

    // ---- layer 2 ----
    gemm_mfma<<<1024, 256, 0, stream>>>(ahi, alo, W2, nullptr, hhi, hlo, N, 0);
    gather_agg_split<<<4096, 256, 0, stream>>>(hhi, hlo, erec, off, dinv, b2, ahi, alo, N);

    // ---- layer 3 ----
    gemm_mfma<<<1024, 256, 0, stream>>>(ahi, alo, W3, nullptr, hhi, hlo, N, 0);
    gather_agg_split<<<4096, 256, 0, stream>>>(hhi, hlo, erec, off, dinv, b3, ahi, alo, N);

    // ---- lin1 (+bias+relu) -> split bf16 ----
    gemm_mfma<<<1024, 256, 0, stream>>>(ahi, alo, l1w, l1b, hhi, hlo, N, 1);

    // ---- lin2 + log_softmax (MFMA, swapped) ----
    lin2_mfma_lsm<<<512, 256, 0, stream>>>(hhi, hlo, l2w, l2b, outp, N);
}